// Round 1
// baseline (1141.465 us; speedup 1.0000x reference)
//
#include <hip/hip_runtime.h>
#include <hip/hip_bf16.h>

#define BB 4
#define CC 128
#define NN 4096
#define KK 16
#define FLT_BIG 3.402823466e+38f

// ================= KNN: exact 16-NN, matches top_k(-d2) incl. stable tie order =================
// block 256 = 4 waves; each block handles 64 queries; wave w scans candidates [w*1024,(w+1)*1024)
__global__ __launch_bounds__(256) void knn_kernel(const float* __restrict__ p,
                                                  int* __restrict__ outidx)
{
  __shared__ float4 PK[NN];        // x,y,z,|p|^2  (64 KB)
  __shared__ float MD[64 * 67];    // per-query 4 partial lists (dist), pad 67 for banks
  __shared__ int   MI[64 * 67];
  const int b = blockIdx.y;
  const int tid = threadIdx.x;
  const float* pb = p + (size_t)b * 3 * NN;
  for (int m = tid; m < NN; m += 256) {
    float x = pb[m], yv = pb[NN + m], z = pb[2 * NN + m];
    PK[m] = make_float4(x, yv, z, x * x + yv * yv + z * z);
  }
  __syncthreads();
  const int q = tid & 63;
  const int w = tid >> 6;
  const int n = blockIdx.x * 64 + q;
  const float4 qc = PK[n];
  float bd[16]; int bi[16];
#pragma unroll
  for (int t = 0; t < 16; ++t) { bd[t] = FLT_BIG; bi[t] = 0x7fffffff; }
  const int m0 = w * 1024;
  for (int m = m0; m < m0 + 1024; ++m) {
    float4 c = PK[m];
    float d = qc.w + c.w - 2.f * (qc.x * c.x + qc.y * c.y + qc.z * c.z);
    if (d < bd[15]) {
      // branchless ripple insert (all static indices -> stays in VGPRs)
#pragma unroll
      for (int t = 15; t >= 1; --t) {
        bool up  = bd[t - 1] > d;   // shift element down
        bool ins = bd[t] > d;       // original value (descending t: untouched yet)
        float nd = up ? bd[t - 1] : (ins ? d : bd[t]);
        int   ni = up ? bi[t - 1] : (ins ? m : bi[t]);
        bd[t] = nd; bi[t] = ni;
      }
      if (bd[0] > d) { bd[0] = d; bi[0] = m; }
    }
  }
  // dump partial lists
#pragma unroll
  for (int t = 0; t < 16; ++t) {
    MD[q * 67 + w * 16 + t] = bd[t];
    MI[q * 67 + w * 16 + t] = bi[t];
  }
  __syncthreads();
  // merge 4 sorted lists -> 16 smallest, lexicographic (d, idx) = reference tie order
  if (tid < 64) {
    int h0 = 0, h1 = 0, h2 = 0, h3 = 0;
    const int base = tid * 67;
    int* op = outidx + ((size_t)b * NN + blockIdx.x * 64 + tid) * KK;
    for (int o = 0; o < KK; ++o) {
      float d0 = (h0 < 16) ? MD[base + h0]      : FLT_BIG;
      float d1 = (h1 < 16) ? MD[base + 16 + h1] : FLT_BIG;
      float d2 = (h2 < 16) ? MD[base + 32 + h2] : FLT_BIG;
      float d3 = (h3 < 16) ? MD[base + 48 + h3] : FLT_BIG;
      int i0 = (h0 < 16) ? MI[base + h0]      : 0x7fffffff;
      int i1 = (h1 < 16) ? MI[base + 16 + h1] : 0x7fffffff;
      int i2 = (h2 < 16) ? MI[base + 32 + h2] : 0x7fffffff;
      int i3 = (h3 < 16) ? MI[base + 48 + h3] : 0x7fffffff;
      float bdv = d0; int biv = i0; int bw = 0;
      if (d1 < bdv || (d1 == bdv && i1 < biv)) { bdv = d1; biv = i1; bw = 1; }
      if (d2 < bdv || (d2 == bdv && i2 < biv)) { bdv = d2; biv = i2; bw = 2; }
      if (d3 < bdv || (d3 == bdv && i3 < biv)) { bdv = d3; biv = i3; bw = 3; }
      op[o] = biv;
      h0 += (bw == 0); h1 += (bw == 1); h2 += (bw == 2); h3 += (bw == 3);
    }
  }
}

// ================= f32 GEMM: out[b] = W(64 rows) @ In[b] (+bias)(+res), opt transposed out ====
// grid (NN/64, CC/64, BB); block 128 (ty16 x tx8); tile 64(C) x 64(N); micro 4x8
__global__ __launch_bounds__(128) void gemm_kernel(const float* __restrict__ In,
                                                   const float* __restrict__ W,
                                                   const float* __restrict__ bias,
                                                   const float* __restrict__ res,
                                                   float* __restrict__ Out,
                                                   int trans_out)
{
  __shared__ float Xs[128][68];   // K x n-tile, 16B-aligned rows
  __shared__ float Ws[16][68];    // j-chunk x c (transposed W)
  const int b = blockIdx.z, c0 = blockIdx.y * 64, n0 = blockIdx.x * 64;
  const int tid = threadIdx.x;
  const int tx = tid & 7, ty = tid >> 3;
  const float* Inb = In + (size_t)b * CC * NN;
  {
    int qq = tid & 15, r0 = tid >> 4;
#pragma unroll
    for (int i = 0; i < 16; ++i) {
      int j = r0 + i * 8;
      float4 v = *(const float4*)&Inb[(size_t)j * NN + n0 + qq * 4];
      *(float4*)&Xs[j][qq * 4] = v;
    }
  }
  __syncthreads();
  float acc[4][8];
#pragma unroll
  for (int i = 0; i < 4; ++i)
#pragma unroll
    for (int j = 0; j < 8; ++j) acc[i][j] = 0.f;

  for (int ch = 0; ch < 8; ++ch) {
    {
      int c = tid & 63, jh = tid >> 6;
      const float* wp = &W[(size_t)(c0 + c) * 128 + ch * 16 + jh * 8];
      float4 w0 = *(const float4*)wp;
      float4 w1 = *(const float4*)(wp + 4);
      int r = jh * 8;
      Ws[r + 0][c] = w0.x; Ws[r + 1][c] = w0.y; Ws[r + 2][c] = w0.z; Ws[r + 3][c] = w0.w;
      Ws[r + 4][c] = w1.x; Ws[r + 5][c] = w1.y; Ws[r + 6][c] = w1.z; Ws[r + 7][c] = w1.w;
    }
    __syncthreads();
#pragma unroll
    for (int jj = 0; jj < 16; ++jj) {
      float4 a  = *(const float4*)&Ws[jj][ty * 4];
      float4 b0 = *(const float4*)&Xs[ch * 16 + jj][tx * 8];
      float4 b1 = *(const float4*)&Xs[ch * 16 + jj][tx * 8 + 4];
      float av[4]  = {a.x, a.y, a.z, a.w};
      float b0v[4] = {b0.x, b0.y, b0.z, b0.w};
      float b1v[4] = {b1.x, b1.y, b1.z, b1.w};
#pragma unroll
      for (int i = 0; i < 4; ++i)
#pragma unroll
        for (int j = 0; j < 4; ++j) {
          acc[i][j]     += av[i] * b0v[j];
          acc[i][j + 4] += av[i] * b1v[j];
        }
    }
    __syncthreads();
  }
  float4 bs = *(const float4*)&bias[c0 + ty * 4];
  float bv[4] = {bs.x, bs.y, bs.z, bs.w};
#pragma unroll
  for (int i = 0; i < 4; ++i)
#pragma unroll
    for (int j = 0; j < 8; ++j) acc[i][j] += bv[i];
  if (res) {
#pragma unroll
    for (int i = 0; i < 4; ++i) {
      const float* rp = &res[((size_t)b * CC + c0 + ty * 4 + i) * NN + n0 + tx * 8];
      float4 r0 = *(const float4*)rp;
      float4 r1 = *(const float4*)(rp + 4);
      acc[i][0] += r0.x; acc[i][1] += r0.y; acc[i][2] += r0.z; acc[i][3] += r0.w;
      acc[i][4] += r1.x; acc[i][5] += r1.y; acc[i][6] += r1.z; acc[i][7] += r1.w;
    }
  }
  if (trans_out) {
#pragma unroll
    for (int j = 0; j < 8; ++j) {
      float4 v = make_float4(acc[0][j], acc[1][j], acc[2][j], acc[3][j]);
      *(float4*)&Out[((size_t)b * NN + n0 + tx * 8 + j) * CC + c0 + ty * 4] = v;
    }
  } else {
#pragma unroll
    for (int i = 0; i < 4; ++i) {
      float* outp = &Out[((size_t)b * CC + c0 + ty * 4 + i) * NN + n0 + tx * 8];
      *(float4*)outp       = make_float4(acc[i][0], acc[i][1], acc[i][2], acc[i][3]);
      *(float4*)(outp + 4) = make_float4(acc[i][4], acc[i][5], acc[i][6], acc[i][7]);
    }
  }
}

// ================= Fused per-neighbor core: pos MLP + gamma MLP + softmax + combine ===========
// grid (NN/4, BB); block 256 (ty16 x tx16); 4 points -> 64 columns (pt*16+k); micro 8x4
#define TNP 4
__global__ __launch_bounds__(256, 2) void fused_kernel(
    const float* __restrict__ p, const int* __restrict__ idxg,
    const float* __restrict__ phi_t, const float* __restrict__ psi_t,
    const float* __restrict__ alp_t,
    const float* __restrict__ d1W, const float* __restrict__ d1b,
    const float* __restrict__ d2W, const float* __restrict__ d2b,
    const float* __restrict__ g1W, const float* __restrict__ g1b,
    const float* __restrict__ g2W, const float* __restrict__ g2b,
    float* __restrict__ y)
{
  __shared__ float bufA[128][68];
  __shared__ float bufB[128][68];
  __shared__ float Ws[16][132];
  __shared__ float rel0[64], rel1[64], rel2[64];
  __shared__ int idxs[64];
  __shared__ float pcen[3][TNP];
  const int b = blockIdx.y;
  const int n0 = blockIdx.x * TNP;
  const int tid = threadIdx.x;
  const int tx = tid & 15, ty = tid >> 4;

  if (tid < 64) idxs[tid] = idxg[((size_t)b * NN + n0 + (tid >> 4)) * KK + (tid & 15)];
  if (tid >= 64 && tid < 64 + 3 * TNP) {
    int t2 = tid - 64; int ax = t2 / TNP, pt = t2 % TNP;
    pcen[ax][pt] = p[((size_t)b * 3 + ax) * NN + n0 + pt];
  }
  __syncthreads();
  if (tid < 64) {
    int j = idxs[tid]; int pt = tid >> 4;
    rel0[tid] = pcen[0][pt] - p[((size_t)b * 3 + 0) * NN + j];
    rel1[tid] = pcen[1][pt] - p[((size_t)b * 3 + 1) * NN + j];
    rel2[tid] = pcen[2][pt] - p[((size_t)b * 3 + 2) * NN + j];
  }
  __syncthreads();
  // stage A: pos1 = relu(d1W @ rel + d1b) into bufA[j][col]
  {
    int col = tid & 63, half = tid >> 6;
    float r0 = rel0[col], r1 = rel1[col], r2 = rel2[col];
#pragma unroll 4
    for (int pass = 0; pass < 32; ++pass) {
      int j = pass * 4 + half;
      float w0 = d1W[j * 3 + 0], w1 = d1W[j * 3 + 1], w2 = d1W[j * 3 + 2];
      bufA[j][col] = fmaxf(w0 * r0 + w1 * r1 + w2 * r2 + d1b[j], 0.f);
    }
  }
  __syncthreads();

  float acc[8][4];
#define MATMUL(BUF, WP) do {                                                        \
  _Pragma("unroll") for (int i_ = 0; i_ < 8; ++i_)                                  \
    _Pragma("unroll") for (int j_ = 0; j_ < 4; ++j_) acc[i_][j_] = 0.f;             \
  for (int ch = 0; ch < 8; ++ch) {                                                  \
    { int c_ = tid >> 1, jh_ = tid & 1;                                             \
      const float* wp_ = &(WP)[(size_t)c_ * 128 + ch * 16 + jh_ * 8];               \
      float4 w0_ = *(const float4*)wp_;                                             \
      float4 w1_ = *(const float4*)(wp_ + 4);                                       \
      int r_ = jh_ * 8;                                                             \
      Ws[r_ + 0][c_] = w0_.x; Ws[r_ + 1][c_] = w0_.y;                               \
      Ws[r_ + 2][c_] = w0_.z; Ws[r_ + 3][c_] = w0_.w;                               \
      Ws[r_ + 4][c_] = w1_.x; Ws[r_ + 5][c_] = w1_.y;                               \
      Ws[r_ + 6][c_] = w1_.z; Ws[r_ + 7][c_] = w1_.w; }                             \
    __syncthreads();                                                                \
    _Pragma("unroll") for (int jj = 0; jj < 16; ++jj) {                             \
      float4 a0_ = *(const float4*)&Ws[jj][ty * 8];                                 \
      float4 a1_ = *(const float4*)&Ws[jj][ty * 8 + 4];                             \
      float4 bv_ = *(const float4*)&(BUF)[ch * 16 + jj][tx * 4];                    \
      float av_[8] = {a0_.x, a0_.y, a0_.z, a0_.w, a1_.x, a1_.y, a1_.z, a1_.w};      \
      float bb_[4] = {bv_.x, bv_.y, bv_.z, bv_.w};                                  \
      _Pragma("unroll") for (int i_ = 0; i_ < 8; ++i_)                              \
        _Pragma("unroll") for (int j_ = 0; j_ < 4; ++j_)                            \
          acc[i_][j_] += av_[i_] * bb_[j_];                                         \
    }                                                                               \
    __syncthreads();                                                                \
  } } while (0)

  // pos = d2W @ pos1 + d2b   (kept in registers)
  MATMUL(bufA, d2W);
  float pos[8][4];
  {
    float4 t0 = *(const float4*)&d2b[ty * 8];
    float4 t1 = *(const float4*)&d2b[ty * 8 + 4];
    float bvv[8] = {t0.x, t0.y, t0.z, t0.w, t1.x, t1.y, t1.z, t1.w};
#pragma unroll
    for (int i = 0; i < 8; ++i)
#pragma unroll
      for (int j = 0; j < 4; ++j) pos[i][j] = acc[i][j] + bvv[i];
  }
  // ain base = pos (overwrite pos1; MATMUL's trailing barrier makes this safe)
#pragma unroll
  for (int i = 0; i < 8; ++i)
    *(float4*)&bufA[ty * 8 + i][tx * 4] =
        make_float4(pos[i][0], pos[i][1], pos[i][2], pos[i][3]);
  __syncthreads();
  // stage C: ain += phi[n] - psi[idx]   (psi_t/phi_t stored [N][C] -> contiguous c reads)
#pragma unroll
  for (int pass = 0; pass < 8; ++pass) {
    int c = pass * 16 + (tid >> 4);
    int colq = tid & 15;
    int col0 = colq * 4;
    int n = n0 + (col0 >> 4);
    float ph = phi_t[((size_t)b * NN + n) * CC + c];
    int j0 = idxs[col0 + 0], j1 = idxs[col0 + 1], j2 = idxs[col0 + 2], j3 = idxs[col0 + 3];
    float4 v = *(float4*)&bufA[c][col0];
    v.x += ph - psi_t[((size_t)b * NN + j0) * CC + c];
    v.y += ph - psi_t[((size_t)b * NN + j1) * CC + c];
    v.z += ph - psi_t[((size_t)b * NN + j2) * CC + c];
    v.w += ph - psi_t[((size_t)b * NN + j3) * CC + c];
    *(float4*)&bufA[c][col0] = v;
  }
  __syncthreads();
  // h = relu(g1W @ ain + g1b) -> bufB
  MATMUL(bufA, g1W);
  {
    float4 t0 = *(const float4*)&g1b[ty * 8];
    float4 t1 = *(const float4*)&g1b[ty * 8 + 4];
    float bvv[8] = {t0.x, t0.y, t0.z, t0.w, t1.x, t1.y, t1.z, t1.w};
#pragma unroll
    for (int i = 0; i < 8; ++i)
      *(float4*)&bufB[ty * 8 + i][tx * 4] =
          make_float4(fmaxf(acc[i][0] + bvv[i], 0.f), fmaxf(acc[i][1] + bvv[i], 0.f),
                      fmaxf(acc[i][2] + bvv[i], 0.f), fmaxf(acc[i][3] + bvv[i], 0.f));
  }
  __syncthreads();
  // attn = g2W @ h + g2b
  MATMUL(bufB, g2W);
  {
    float4 t0 = *(const float4*)&g2b[ty * 8];
    float4 t1 = *(const float4*)&g2b[ty * 8 + 4];
    float bvv[8] = {t0.x, t0.y, t0.z, t0.w, t1.x, t1.y, t1.z, t1.w};
#pragma unroll
    for (int i = 0; i < 8; ++i)
#pragma unroll
      for (int j = 0; j < 4; ++j) acc[i][j] += bvv[i];
  }
  // softmax over 16 k per (c, point): group = 4 lanes (tx & ~3)
#pragma unroll
  for (int i = 0; i < 8; ++i) {
    float m = fmaxf(fmaxf(acc[i][0], acc[i][1]), fmaxf(acc[i][2], acc[i][3]));
    m = fmaxf(m, __shfl_xor(m, 1));
    m = fmaxf(m, __shfl_xor(m, 2));
    float s = 0.f;
#pragma unroll
    for (int j = 0; j < 4; ++j) { float e = __expf(acc[i][j] - m); acc[i][j] = e; s += e; }
    s += __shfl_xor(s, 1);
    s += __shfl_xor(s, 2);
    float inv = 1.f / s;
#pragma unroll
    for (int j = 0; j < 4; ++j) acc[i][j] *= inv;
  }
  // combine: y[c,n] = sum_k w * (alpha[idx] + pos)
  float yacc[8] = {0.f, 0.f, 0.f, 0.f, 0.f, 0.f, 0.f, 0.f};
#pragma unroll
  for (int j = 0; j < 4; ++j) {
    int jg = idxs[tx * 4 + j];
    const float* ap = &alp_t[((size_t)b * NN + jg) * CC + ty * 8];
    float4 a0 = *(const float4*)ap;
    float4 a1 = *(const float4*)(ap + 4);
    float av[8] = {a0.x, a0.y, a0.z, a0.w, a1.x, a1.y, a1.z, a1.w};
#pragma unroll
    for (int i = 0; i < 8; ++i) yacc[i] += acc[i][j] * (av[i] + pos[i][j]);
  }
#pragma unroll
  for (int i = 0; i < 8; ++i) {
    float v = yacc[i];
    v += __shfl_xor(v, 1);
    v += __shfl_xor(v, 2);
    if ((tx & 3) == 0)
      y[((size_t)b * CC + ty * 8 + i) * NN + n0 + (tx >> 2)] = v;
  }
#undef MATMUL
}

// =============================================================================================
extern "C" void kernel_launch(void* const* d_in, const int* in_sizes, int n_in,
                              void* d_out, int out_size, void* d_ws, size_t ws_size,
                              hipStream_t stream) {
  const float* input_p = (const float*)d_in[0];
  const float* input_x = (const float*)d_in[1];
  const float* top_W   = (const float*)d_in[2];  const float* top_b   = (const float*)d_in[3];
  const float* down_W  = (const float*)d_in[4];  const float* down_b  = (const float*)d_in[5];
  const float* phi_W   = (const float*)d_in[6];  const float* phi_b   = (const float*)d_in[7];
  const float* psi_W   = (const float*)d_in[8];  const float* psi_b   = (const float*)d_in[9];
  const float* alpha_W = (const float*)d_in[10]; const float* alpha_b = (const float*)d_in[11];
  const float* g1_W    = (const float*)d_in[12]; const float* g1_b    = (const float*)d_in[13];
  const float* g2_W    = (const float*)d_in[14]; const float* g2_b    = (const float*)d_in[15];
  const float* d1_W    = (const float*)d_in[16]; const float* d1_b    = (const float*)d_in[17];
  const float* d2_W    = (const float*)d_in[18]; const float* d2_b    = (const float*)d_in[19];
  float* out = (float*)d_out;

  char* ws = (char*)d_ws;
  int*   ws_idx = (int*)ws;                              // 1 MB: [B][N][16]
  float* ws_x   = (float*)(ws + (size_t)1 * (1 << 20));  // 8 MB: [B][C][N]
  float* ws_phi = (float*)(ws + (size_t)9 * (1 << 20));  // 8 MB: [B][N][C]
  float* ws_psi = (float*)(ws + (size_t)17 * (1 << 20)); // 8 MB: [B][N][C]
  float* ws_alp = (float*)(ws + (size_t)25 * (1 << 20)); // 8 MB: [B][N][C]
  float* ws_y   = (float*)(ws + (size_t)33 * (1 << 20)); // 8 MB: [B][C][N]

  knn_kernel<<<dim3(NN / 64, BB), 256, 0, stream>>>(input_p, ws_idx);
  gemm_kernel<<<dim3(NN / 64, 2, BB), 128, 0, stream>>>(input_x, top_W, top_b, nullptr, ws_x, 0);
  gemm_kernel<<<dim3(NN / 64, 2, BB), 128, 0, stream>>>(ws_x, phi_W, phi_b, nullptr, ws_phi, 1);
  gemm_kernel<<<dim3(NN / 64, 2, BB), 128, 0, stream>>>(ws_x, psi_W, psi_b, nullptr, ws_psi, 1);
  gemm_kernel<<<dim3(NN / 64, 2, BB), 128, 0, stream>>>(ws_x, alpha_W, alpha_b, nullptr, ws_alp, 1);
  fused_kernel<<<dim3(NN / TNP, BB), 256, 0, stream>>>(input_p, ws_idx, ws_phi, ws_psi, ws_alp,
                                                       d1_W, d1_b, d2_W, d2_b,
                                                       g1_W, g1_b, g2_W, g2_b, ws_y);
  gemm_kernel<<<dim3(NN / 64, 2, BB), 128, 0, stream>>>(ws_y, down_W, down_b, input_x, out, 0);
}

// Round 2
// 713.074 us; speedup vs baseline: 1.6008x; 1.6008x over previous
//
#include <hip/hip_runtime.h>
#include <hip/hip_bf16.h>

#define BB 4
#define CC 128
#define NN 4096
#define KK 16
#define FLT_BIG 3.402823466e+38f

// ---- shared distance: identical instruction sequence everywhere (bit-exact re-eval) ----
__device__ __forceinline__ float dist4(const float4 q, const float4 c) {
  float t = __fmaf_rn(q.x, c.x, __fmaf_rn(q.y, c.y, __fmul_rn(q.z, c.z)));
  return __fmaf_rn(-2.f, t, q.w + c.w);
}

// ================= prep: pack p -> (x,y,z,|p|^2) float4 =================
__global__ __launch_bounds__(256) void prep_kernel(const float* __restrict__ p,
                                                   float4* __restrict__ pkg) {
  int i = blockIdx.x * 256 + threadIdx.x;   // 0..B*N-1
  int b = i >> 12, m = i & (NN - 1);
  const float* pb = p + (size_t)b * 3 * NN;
  float x = pb[m], y = pb[NN + m], z = pb[2 * NN + m];
  pkg[i] = make_float4(x, y, z, __fmaf_rn(x, x, __fmaf_rn(y, y, __fmul_rn(z, z))));
}

// ================= KNN: exact 16-NN set (order-free; boundary ties -> lowest index) ======
// block 512 = 8 waves; 64 queries/block (lane = query); wave w scans candidates [w*512,(w+1)*512)
// pass1: per-wave sorted top-16 DISTANCES via unconditional med3 ripple (no divergence)
// merge: 8-way value merge -> global 16th-smallest threshold T per query
// pass2: rescan, collect idx with d <= T (rare predicated LDS-atomic append)
__global__ __launch_bounds__(512, 2) void knn_kernel(const float4* __restrict__ pkg,
                                                     int* __restrict__ outidx)
{
  __shared__ float BD[8][64][17];   // per-wave sorted dists (pad 17 vs banks)
  __shared__ float TS[64];
  __shared__ int   CNT[64];
  __shared__ float COLd[64][20];
  __shared__ int   COLi[64][20];
  const int b = blockIdx.y;
  const int tid = threadIdx.x;
  const int lane = tid & 63;        // query within block
  const int w = tid >> 6;           // wave 0..7
  const int n = blockIdx.x * 64 + lane;
  const float4* PB = pkg + (size_t)b * NN;
  const float4 qc = PB[n];
  if (tid < 64) CNT[tid] = 0;

  float bd[16];
#pragma unroll
  for (int t = 0; t < 16; ++t) bd[t] = FLT_BIG;
  const int m0 = w * 512;
#pragma unroll 4
  for (int m = m0; m < m0 + 512; ++m) {
    float4 c = PB[m];
    float d = dist4(qc, c);
    // branchless sorted multiset-insert: all reads are OLD values (descending t)
#pragma unroll
    for (int t = 15; t >= 1; --t) bd[t] = __builtin_amdgcn_fmed3f(bd[t - 1], d, bd[t]);
    bd[0] = fminf(bd[0], d);
  }
#pragma unroll
  for (int t = 0; t < 16; ++t) BD[w][lane][t] = bd[t];
  __syncthreads();

  // ---- 8-way merge of sorted value lists: T = 16th smallest of union ----
  if (tid < 64) {
    const int q = tid;
    int h0 = 0, h1 = 0, h2 = 0, h3 = 0, h4 = 0, h5 = 0, h6 = 0, h7 = 0;
    float mv = FLT_BIG;
#pragma unroll 1
    for (int r = 0; r < 16; ++r) {
      float v0 = BD[0][q][h0], v1 = BD[1][q][h1], v2 = BD[2][q][h2], v3 = BD[3][q][h3];
      float v4 = BD[4][q][h4], v5 = BD[5][q][h5], v6 = BD[6][q][h6], v7 = BD[7][q][h7];
      mv = v0; int mw = 0;
      if (v1 < mv) { mv = v1; mw = 1; }
      if (v2 < mv) { mv = v2; mw = 2; }
      if (v3 < mv) { mv = v3; mw = 3; }
      if (v4 < mv) { mv = v4; mw = 4; }
      if (v5 < mv) { mv = v5; mw = 5; }
      if (v6 < mv) { mv = v6; mw = 6; }
      if (v7 < mv) { mv = v7; mw = 7; }
      h0 += (mw == 0); h1 += (mw == 1); h2 += (mw == 2); h3 += (mw == 3);
      h4 += (mw == 4); h5 += (mw == 5); h6 += (mw == 6); h7 += (mw == 7);
    }
    TS[q] = mv;
  }
  __syncthreads();

  // ---- pass 2: collect all candidates with d <= T (bit-identical d) ----
  {
    const float thr = TS[lane];
#pragma unroll 4
    for (int m = m0; m < m0 + 512; ++m) {
      float4 c = PB[m];
      float d = dist4(qc, c);
      if (d <= thr) {
        int pos = atomicAdd(&CNT[lane], 1);
        if (pos < 20) { COLd[lane][pos] = d; COLi[lane][pos] = m; }
      }
    }
  }
  __syncthreads();

  // ---- writeout (set semantics; exact boundary-tie rule on cold path) ----
  if (tid < 64) {
    const int q = tid;
    int c = CNT[q]; if (c > 20) c = 20;
    int* op = outidx + ((size_t)b * NN + blockIdx.x * 64 + q) * KK;
    if (c == KK) {
#pragma unroll
      for (int o = 0; o < KK; ++o) op[o] = COLi[q][o];
    } else {
      const float T = TS[q];
      int less = 0;
      for (int s = 0; s < c; ++s) less += (COLd[q][s] < T);
      int need = KK - less;
      int o = 0;
      for (int s = 0; s < c; ++s)
        if (COLd[q][s] < T) op[o++] = COLi[q][s];
      for (int s = 0; s < c; ++s) {
        if (COLd[q][s] == T) {
          int idx = COLi[q][s];
          int rank = 0;
          for (int s2 = 0; s2 < c; ++s2)
            rank += (COLd[q][s2] == T && COLi[q][s2] < idx);
          if (rank < need) op[o++] = idx;
        }
      }
    }
  }
}

// ================= f32 GEMM: out[b] = W(64 rows) @ In[b] (+bias)(+res), opt transposed out ====
// grid (NN/64, CC/64, BB); block 128 (ty16 x tx8); tile 64(C) x 64(N); micro 4x8
__global__ __launch_bounds__(128) void gemm_kernel(const float* __restrict__ In,
                                                   const float* __restrict__ W,
                                                   const float* __restrict__ bias,
                                                   const float* __restrict__ res,
                                                   float* __restrict__ Out,
                                                   int trans_out)
{
  __shared__ float Xs[128][68];   // K x n-tile, 16B-aligned rows
  __shared__ float Ws[16][68];    // j-chunk x c (transposed W)
  const int b = blockIdx.z, c0 = blockIdx.y * 64, n0 = blockIdx.x * 64;
  const int tid = threadIdx.x;
  const int tx = tid & 7, ty = tid >> 3;
  const float* Inb = In + (size_t)b * CC * NN;
  {
    int qq = tid & 15, r0 = tid >> 4;
#pragma unroll
    for (int i = 0; i < 16; ++i) {
      int j = r0 + i * 8;
      float4 v = *(const float4*)&Inb[(size_t)j * NN + n0 + qq * 4];
      *(float4*)&Xs[j][qq * 4] = v;
    }
  }
  __syncthreads();
  float acc[4][8];
#pragma unroll
  for (int i = 0; i < 4; ++i)
#pragma unroll
    for (int j = 0; j < 8; ++j) acc[i][j] = 0.f;

  for (int ch = 0; ch < 8; ++ch) {
    {
      int c = tid & 63, jh = tid >> 6;
      const float* wp = &W[(size_t)(c0 + c) * 128 + ch * 16 + jh * 8];
      float4 w0 = *(const float4*)wp;
      float4 w1 = *(const float4*)(wp + 4);
      int r = jh * 8;
      Ws[r + 0][c] = w0.x; Ws[r + 1][c] = w0.y; Ws[r + 2][c] = w0.z; Ws[r + 3][c] = w0.w;
      Ws[r + 4][c] = w1.x; Ws[r + 5][c] = w1.y; Ws[r + 6][c] = w1.z; Ws[r + 7][c] = w1.w;
    }
    __syncthreads();
#pragma unroll
    for (int jj = 0; jj < 16; ++jj) {
      float4 a  = *(const float4*)&Ws[jj][ty * 4];
      float4 b0 = *(const float4*)&Xs[ch * 16 + jj][tx * 8];
      float4 b1 = *(const float4*)&Xs[ch * 16 + jj][tx * 8 + 4];
      float av[4]  = {a.x, a.y, a.z, a.w};
      float b0v[4] = {b0.x, b0.y, b0.z, b0.w};
      float b1v[4] = {b1.x, b1.y, b1.z, b1.w};
#pragma unroll
      for (int i = 0; i < 4; ++i)
#pragma unroll
        for (int j = 0; j < 4; ++j) {
          acc[i][j]     += av[i] * b0v[j];
          acc[i][j + 4] += av[i] * b1v[j];
        }
    }
    __syncthreads();
  }
  float4 bs = *(const float4*)&bias[c0 + ty * 4];
  float bv[4] = {bs.x, bs.y, bs.z, bs.w};
#pragma unroll
  for (int i = 0; i < 4; ++i)
#pragma unroll
    for (int j = 0; j < 8; ++j) acc[i][j] += bv[i];
  if (res) {
#pragma unroll
    for (int i = 0; i < 4; ++i) {
      const float* rp = &res[((size_t)b * CC + c0 + ty * 4 + i) * NN + n0 + tx * 8];
      float4 r0 = *(const float4*)rp;
      float4 r1 = *(const float4*)(rp + 4);
      acc[i][0] += r0.x; acc[i][1] += r0.y; acc[i][2] += r0.z; acc[i][3] += r0.w;
      acc[i][4] += r1.x; acc[i][5] += r1.y; acc[i][6] += r1.z; acc[i][7] += r1.w;
    }
  }
  if (trans_out) {
#pragma unroll
    for (int j = 0; j < 8; ++j) {
      float4 v = make_float4(acc[0][j], acc[1][j], acc[2][j], acc[3][j]);
      *(float4*)&Out[((size_t)b * NN + n0 + tx * 8 + j) * CC + c0 + ty * 4] = v;
    }
  } else {
#pragma unroll
    for (int i = 0; i < 4; ++i) {
      float* outp = &Out[((size_t)b * CC + c0 + ty * 4 + i) * NN + n0 + tx * 8];
      *(float4*)outp       = make_float4(acc[i][0], acc[i][1], acc[i][2], acc[i][3]);
      *(float4*)(outp + 4) = make_float4(acc[i][4], acc[i][5], acc[i][6], acc[i][7]);
    }
  }
}

// ================= Fused per-neighbor core: pos MLP + gamma MLP + softmax + combine ===========
// grid (NN/4, BB); block 256 (ty16 x tx16); 4 points -> 64 columns (pt*16+k); micro 8x4
#define TNP 4
__global__ __launch_bounds__(256, 2) void fused_kernel(
    const float* __restrict__ p, const int* __restrict__ idxg,
    const float* __restrict__ phi_t, const float* __restrict__ psi_t,
    const float* __restrict__ alp_t,
    const float* __restrict__ d1W, const float* __restrict__ d1b,
    const float* __restrict__ d2W, const float* __restrict__ d2b,
    const float* __restrict__ g1W, const float* __restrict__ g1b,
    const float* __restrict__ g2W, const float* __restrict__ g2b,
    float* __restrict__ y)
{
  __shared__ float bufA[128][68];
  __shared__ float bufB[128][68];
  __shared__ float Ws[16][132];
  __shared__ float rel0[64], rel1[64], rel2[64];
  __shared__ int idxs[64];
  __shared__ float pcen[3][TNP];
  const int b = blockIdx.y;
  const int n0 = blockIdx.x * TNP;
  const int tid = threadIdx.x;
  const int tx = tid & 15, ty = tid >> 4;

  if (tid < 64) idxs[tid] = idxg[((size_t)b * NN + n0 + (tid >> 4)) * KK + (tid & 15)];
  if (tid >= 64 && tid < 64 + 3 * TNP) {
    int t2 = tid - 64; int ax = t2 / TNP, pt = t2 % TNP;
    pcen[ax][pt] = p[((size_t)b * 3 + ax) * NN + n0 + pt];
  }
  __syncthreads();
  if (tid < 64) {
    int j = idxs[tid]; int pt = tid >> 4;
    rel0[tid] = pcen[0][pt] - p[((size_t)b * 3 + 0) * NN + j];
    rel1[tid] = pcen[1][pt] - p[((size_t)b * 3 + 1) * NN + j];
    rel2[tid] = pcen[2][pt] - p[((size_t)b * 3 + 2) * NN + j];
  }
  __syncthreads();
  // stage A: pos1 = relu(d1W @ rel + d1b) into bufA[j][col]
  {
    int col = tid & 63, half = tid >> 6;
    float r0 = rel0[col], r1 = rel1[col], r2 = rel2[col];
#pragma unroll 4
    for (int pass = 0; pass < 32; ++pass) {
      int j = pass * 4 + half;
      float w0 = d1W[j * 3 + 0], w1 = d1W[j * 3 + 1], w2 = d1W[j * 3 + 2];
      bufA[j][col] = fmaxf(w0 * r0 + w1 * r1 + w2 * r2 + d1b[j], 0.f);
    }
  }
  __syncthreads();

  float acc[8][4];
#define MATMUL(BUF, WP) do {                                                        \
  _Pragma("unroll") for (int i_ = 0; i_ < 8; ++i_)                                  \
    _Pragma("unroll") for (int j_ = 0; j_ < 4; ++j_) acc[i_][j_] = 0.f;             \
  for (int ch = 0; ch < 8; ++ch) {                                                  \
    { int c_ = tid >> 1, jh_ = tid & 1;                                             \
      const float* wp_ = &(WP)[(size_t)c_ * 128 + ch * 16 + jh_ * 8];               \
      float4 w0_ = *(const float4*)wp_;                                             \
      float4 w1_ = *(const float4*)(wp_ + 4);                                       \
      int r_ = jh_ * 8;                                                             \
      Ws[r_ + 0][c_] = w0_.x; Ws[r_ + 1][c_] = w0_.y;                               \
      Ws[r_ + 2][c_] = w0_.z; Ws[r_ + 3][c_] = w0_.w;                               \
      Ws[r_ + 4][c_] = w1_.x; Ws[r_ + 5][c_] = w1_.y;                               \
      Ws[r_ + 6][c_] = w1_.z; Ws[r_ + 7][c_] = w1_.w; }                             \
    __syncthreads();                                                                \
    _Pragma("unroll") for (int jj = 0; jj < 16; ++jj) {                             \
      float4 a0_ = *(const float4*)&Ws[jj][ty * 8];                                 \
      float4 a1_ = *(const float4*)&Ws[jj][ty * 8 + 4];                             \
      float4 bv_ = *(const float4*)&(BUF)[ch * 16 + jj][tx * 4];                    \
      float av_[8] = {a0_.x, a0_.y, a0_.z, a0_.w, a1_.x, a1_.y, a1_.z, a1_.w};      \
      float bb_[4] = {bv_.x, bv_.y, bv_.z, bv_.w};                                  \
      _Pragma("unroll") for (int i_ = 0; i_ < 8; ++i_)                              \
        _Pragma("unroll") for (int j_ = 0; j_ < 4; ++j_)                            \
          acc[i_][j_] += av_[i_] * bb_[j_];                                         \
    }                                                                               \
    __syncthreads();                                                                \
  } } while (0)

  // pos = d2W @ pos1 + d2b   (kept in registers)
  MATMUL(bufA, d2W);
  float pos[8][4];
  {
    float4 t0 = *(const float4*)&d2b[ty * 8];
    float4 t1 = *(const float4*)&d2b[ty * 8 + 4];
    float bvv[8] = {t0.x, t0.y, t0.z, t0.w, t1.x, t1.y, t1.z, t1.w};
#pragma unroll
    for (int i = 0; i < 8; ++i)
#pragma unroll
      for (int j = 0; j < 4; ++j) pos[i][j] = acc[i][j] + bvv[i];
  }
  // ain base = pos (overwrite pos1; MATMUL's trailing barrier makes this safe)
#pragma unroll
  for (int i = 0; i < 8; ++i)
    *(float4*)&bufA[ty * 8 + i][tx * 4] =
        make_float4(pos[i][0], pos[i][1], pos[i][2], pos[i][3]);
  __syncthreads();
  // stage C: ain += phi[n] - psi[idx]   (psi_t/phi_t stored [N][C] -> contiguous c reads)
#pragma unroll
  for (int pass = 0; pass < 8; ++pass) {
    int c = pass * 16 + (tid >> 4);
    int colq = tid & 15;
    int col0 = colq * 4;
    int n = n0 + (col0 >> 4);
    float ph = phi_t[((size_t)b * NN + n) * CC + c];
    int j0 = idxs[col0 + 0], j1 = idxs[col0 + 1], j2 = idxs[col0 + 2], j3 = idxs[col0 + 3];
    float4 v = *(float4*)&bufA[c][col0];
    v.x += ph - psi_t[((size_t)b * NN + j0) * CC + c];
    v.y += ph - psi_t[((size_t)b * NN + j1) * CC + c];
    v.z += ph - psi_t[((size_t)b * NN + j2) * CC + c];
    v.w += ph - psi_t[((size_t)b * NN + j3) * CC + c];
    *(float4*)&bufA[c][col0] = v;
  }
  __syncthreads();
  // h = relu(g1W @ ain + g1b) -> bufB
  MATMUL(bufA, g1W);
  {
    float4 t0 = *(const float4*)&g1b[ty * 8];
    float4 t1 = *(const float4*)&g1b[ty * 8 + 4];
    float bvv[8] = {t0.x, t0.y, t0.z, t0.w, t1.x, t1.y, t1.z, t1.w};
#pragma unroll
    for (int i = 0; i < 8; ++i)
      *(float4*)&bufB[ty * 8 + i][tx * 4] =
          make_float4(fmaxf(acc[i][0] + bvv[i], 0.f), fmaxf(acc[i][1] + bvv[i], 0.f),
                      fmaxf(acc[i][2] + bvv[i], 0.f), fmaxf(acc[i][3] + bvv[i], 0.f));
  }
  __syncthreads();
  // attn = g2W @ h + g2b
  MATMUL(bufB, g2W);
  {
    float4 t0 = *(const float4*)&g2b[ty * 8];
    float4 t1 = *(const float4*)&g2b[ty * 8 + 4];
    float bvv[8] = {t0.x, t0.y, t0.z, t0.w, t1.x, t1.y, t1.z, t1.w};
#pragma unroll
    for (int i = 0; i < 8; ++i)
#pragma unroll
      for (int j = 0; j < 4; ++j) acc[i][j] += bvv[i];
  }
  // softmax over 16 k per (c, point): group = 4 lanes (tx & ~3)
#pragma unroll
  for (int i = 0; i < 8; ++i) {
    float m = fmaxf(fmaxf(acc[i][0], acc[i][1]), fmaxf(acc[i][2], acc[i][3]));
    m = fmaxf(m, __shfl_xor(m, 1));
    m = fmaxf(m, __shfl_xor(m, 2));
    float s = 0.f;
#pragma unroll
    for (int j = 0; j < 4; ++j) { float e = __expf(acc[i][j] - m); acc[i][j] = e; s += e; }
    s += __shfl_xor(s, 1);
    s += __shfl_xor(s, 2);
    float inv = 1.f / s;
#pragma unroll
    for (int j = 0; j < 4; ++j) acc[i][j] *= inv;
  }
  // combine: y[c,n] = sum_k w * (alpha[idx] + pos)
  float yacc[8] = {0.f, 0.f, 0.f, 0.f, 0.f, 0.f, 0.f, 0.f};
#pragma unroll
  for (int j = 0; j < 4; ++j) {
    int jg = idxs[tx * 4 + j];
    const float* ap = &alp_t[((size_t)b * NN + jg) * CC + ty * 8];
    float4 a0 = *(const float4*)ap;
    float4 a1 = *(const float4*)(ap + 4);
    float av[8] = {a0.x, a0.y, a0.z, a0.w, a1.x, a1.y, a1.z, a1.w};
#pragma unroll
    for (int i = 0; i < 8; ++i) yacc[i] += acc[i][j] * (av[i] + pos[i][j]);
  }
#pragma unroll
  for (int i = 0; i < 8; ++i) {
    float v = yacc[i];
    v += __shfl_xor(v, 1);
    v += __shfl_xor(v, 2);
    if ((tx & 3) == 0)
      y[((size_t)b * CC + ty * 8 + i) * NN + n0 + (tx >> 2)] = v;
  }
#undef MATMUL
}

// =============================================================================================
extern "C" void kernel_launch(void* const* d_in, const int* in_sizes, int n_in,
                              void* d_out, int out_size, void* d_ws, size_t ws_size,
                              hipStream_t stream) {
  const float* input_p = (const float*)d_in[0];
  const float* input_x = (const float*)d_in[1];
  const float* top_W   = (const float*)d_in[2];  const float* top_b   = (const float*)d_in[3];
  const float* down_W  = (const float*)d_in[4];  const float* down_b  = (const float*)d_in[5];
  const float* phi_W   = (const float*)d_in[6];  const float* phi_b   = (const float*)d_in[7];
  const float* psi_W   = (const float*)d_in[8];  const float* psi_b   = (const float*)d_in[9];
  const float* alpha_W = (const float*)d_in[10]; const float* alpha_b = (const float*)d_in[11];
  const float* g1_W    = (const float*)d_in[12]; const float* g1_b    = (const float*)d_in[13];
  const float* g2_W    = (const float*)d_in[14]; const float* g2_b    = (const float*)d_in[15];
  const float* d1_W    = (const float*)d_in[16]; const float* d1_b    = (const float*)d_in[17];
  const float* d2_W    = (const float*)d_in[18]; const float* d2_b    = (const float*)d_in[19];
  float* out = (float*)d_out;

  char* ws = (char*)d_ws;
  int*    ws_idx = (int*)ws;                              // 1 MB: [B][N][16]
  float*  ws_x   = (float*)(ws + (size_t)1 * (1 << 20));  // 8 MB: [B][C][N]
  float*  ws_phi = (float*)(ws + (size_t)9 * (1 << 20));  // 8 MB: [B][N][C]
  float*  ws_psi = (float*)(ws + (size_t)17 * (1 << 20)); // 8 MB: [B][N][C]
  float*  ws_alp = (float*)(ws + (size_t)25 * (1 << 20)); // 8 MB: [B][N][C]
  float*  ws_y   = (float*)(ws + (size_t)33 * (1 << 20)); // 8 MB: [B][C][N]
  float4* ws_pkg = (float4*)(ws + (size_t)41 * (1 << 20)); // 256 KB: [B][N] float4

  prep_kernel<<<(BB * NN) / 256, 256, 0, stream>>>(input_p, ws_pkg);
  knn_kernel<<<dim3(NN / 64, BB), 512, 0, stream>>>(ws_pkg, ws_idx);
  gemm_kernel<<<dim3(NN / 64, 2, BB), 128, 0, stream>>>(input_x, top_W, top_b, nullptr, ws_x, 0);
  gemm_kernel<<<dim3(NN / 64, 2, BB), 128, 0, stream>>>(ws_x, phi_W, phi_b, nullptr, ws_phi, 1);
  gemm_kernel<<<dim3(NN / 64, 2, BB), 128, 0, stream>>>(ws_x, psi_W, psi_b, nullptr, ws_psi, 1);
  gemm_kernel<<<dim3(NN / 64, 2, BB), 128, 0, stream>>>(ws_x, alpha_W, alpha_b, nullptr, ws_alp, 1);
  fused_kernel<<<dim3(NN / TNP, BB), 256, 0, stream>>>(input_p, ws_idx, ws_phi, ws_psi, ws_alp,
                                                       d1_W, d1_b, d2_W, d2_b,
                                                       g1_W, g1_b, g2_W, g2_b, ws_y);
  gemm_kernel<<<dim3(NN / 64, 2, BB), 128, 0, stream>>>(ws_y, down_W, down_b, input_x, out, 0);
}

// Round 4
// 495.486 us; speedup vs baseline: 2.3037x; 1.4391x over previous
//
#include <hip/hip_runtime.h>
#include <hip/hip_bf16.h>

#define BB 4
#define CC 128
#define NN 4096
#define KK 16
#define FLT_BIG 3.402823466e+38f

typedef __attribute__((ext_vector_type(8))) short short8v;
typedef __attribute__((ext_vector_type(4))) short short4v;
typedef __attribute__((ext_vector_type(4))) float f32x4;

__device__ __forceinline__ unsigned short f2b(float x) {   // RNE f32->bf16
  union { float f; unsigned u; } v; v.f = x;
  unsigned r = v.u + 0x7fffu + ((v.u >> 16) & 1u);
  return (unsigned short)(r >> 16);
}
__device__ __forceinline__ float b2f(unsigned short h) {
  union { float f; unsigned u; } v; v.u = ((unsigned)h) << 16; return v.f;
}

// ---- shared distance: identical instruction sequence everywhere (bit-exact re-eval) ----
__device__ __forceinline__ float dist4(const float4 q, const float4 c) {
  float t = __fmaf_rn(q.x, c.x, __fmaf_rn(q.y, c.y, __fmul_rn(q.z, c.z)));
  return __fmaf_rn(-2.f, t, q.w + c.w);
}

// ================= prep: pack p -> (x,y,z,|p|^2) float4 =================
__global__ __launch_bounds__(256) void prep_kernel(const float* __restrict__ p,
                                                   float4* __restrict__ pkg) {
  int i = blockIdx.x * 256 + threadIdx.x;   // 0..B*N-1
  int b = i >> 12, m = i & (NN - 1);
  const float* pb = p + (size_t)b * 3 * NN;
  float x = pb[m], y = pb[NN + m], z = pb[2 * NN + m];
  pkg[i] = make_float4(x, y, z, __fmaf_rn(x, x, __fmaf_rn(y, y, __fmul_rn(z, z))));
}

// ================= wprep: pack d2W/g1W/g2W into bf16 MFMA A-fragment-linear layout =========
// layout: wpk[mat(3)][ctile(8)][ks(4)][lane(64)][8]  (halfwords); elem j = W[ct*16+(l&15)][ks*32+(l>>4)*8+j]
__global__ __launch_bounds__(256) void wprep_kernel(const float* __restrict__ d2W,
                                                    const float* __restrict__ g1W,
                                                    const float* __restrict__ g2W,
                                                    unsigned short* __restrict__ wpk) {
  int t = blockIdx.x * 256 + threadIdx.x;         // 0..6143
  int mat = t >> 11, r = t & 2047;
  int ctile = r >> 8, ks = (r >> 6) & 3, lane = r & 63;
  const float* W = (mat == 0) ? d2W : (mat == 1) ? g1W : g2W;
  int row = ctile * 16 + (lane & 15);
  int k0 = ks * 32 + (lane >> 4) * 8;
  const float* src = &W[row * 128 + k0];
  unsigned short* dst = &wpk[(size_t)t * 8];
#pragma unroll
  for (int e = 0; e < 8; ++e) dst[e] = f2b(src[e]);
}

// ================= KNN: exact 16-NN set (order-free; boundary ties -> lowest index) ======
__global__ __launch_bounds__(512, 2) void knn_kernel(const float4* __restrict__ pkg,
                                                     int* __restrict__ outidx)
{
  __shared__ float BD[8][64][17];
  __shared__ float TS[64];
  __shared__ int   CNT[64];
  __shared__ float COLd[64][20];
  __shared__ int   COLi[64][20];
  const int b = blockIdx.y;
  const int tid = threadIdx.x;
  const int lane = tid & 63;
  const int w = tid >> 6;
  const int n = blockIdx.x * 64 + lane;
  const float4* PB = pkg + (size_t)b * NN;
  const float4 qc = PB[n];
  if (tid < 64) CNT[tid] = 0;

  float bd[16];
#pragma unroll
  for (int t = 0; t < 16; ++t) bd[t] = FLT_BIG;
  const int m0 = w * 512;
#pragma unroll 4
  for (int m = m0; m < m0 + 512; ++m) {
    float4 c = PB[m];
    float d = dist4(qc, c);
#pragma unroll
    for (int t = 15; t >= 1; --t) bd[t] = __builtin_amdgcn_fmed3f(bd[t - 1], d, bd[t]);
    bd[0] = fminf(bd[0], d);
  }
#pragma unroll
  for (int t = 0; t < 16; ++t) BD[w][lane][t] = bd[t];
  __syncthreads();

  if (tid < 64) {
    const int q = tid;
    int h0 = 0, h1 = 0, h2 = 0, h3 = 0, h4 = 0, h5 = 0, h6 = 0, h7 = 0;
    float mv = FLT_BIG;
#pragma unroll 1
    for (int r = 0; r < 16; ++r) {
      float v0 = BD[0][q][h0], v1 = BD[1][q][h1], v2 = BD[2][q][h2], v3 = BD[3][q][h3];
      float v4 = BD[4][q][h4], v5 = BD[5][q][h5], v6 = BD[6][q][h6], v7 = BD[7][q][h7];
      mv = v0; int mw = 0;
      if (v1 < mv) { mv = v1; mw = 1; }
      if (v2 < mv) { mv = v2; mw = 2; }
      if (v3 < mv) { mv = v3; mw = 3; }
      if (v4 < mv) { mv = v4; mw = 4; }
      if (v5 < mv) { mv = v5; mw = 5; }
      if (v6 < mv) { mv = v6; mw = 6; }
      if (v7 < mv) { mv = v7; mw = 7; }
      h0 += (mw == 0); h1 += (mw == 1); h2 += (mw == 2); h3 += (mw == 3);
      h4 += (mw == 4); h5 += (mw == 5); h6 += (mw == 6); h7 += (mw == 7);
    }
    TS[q] = mv;
  }
  __syncthreads();

  {
    const float thr = TS[lane];
#pragma unroll 4
    for (int m = m0; m < m0 + 512; ++m) {
      float4 c = PB[m];
      float d = dist4(qc, c);
      if (d <= thr) {
        int pos = atomicAdd(&CNT[lane], 1);
        if (pos < 20) { COLd[lane][pos] = d; COLi[lane][pos] = m; }
      }
    }
  }
  __syncthreads();

  if (tid < 64) {
    const int q = tid;
    int c = CNT[q]; if (c > 20) c = 20;
    int* op = outidx + ((size_t)b * NN + blockIdx.x * 64 + q) * KK;
    if (c == KK) {
#pragma unroll
      for (int o = 0; o < KK; ++o) op[o] = COLi[q][o];
    } else {
      const float T = TS[q];
      int less = 0;
      for (int s = 0; s < c; ++s) less += (COLd[q][s] < T);
      int need = KK - less;
      int o = 0;
      for (int s = 0; s < c; ++s)
        if (COLd[q][s] < T) op[o++] = COLi[q][s];
      for (int s = 0; s < c; ++s) {
        if (COLd[q][s] == T) {
          int idx = COLi[q][s];
          int rank = 0;
          for (int s2 = 0; s2 < c; ++s2)
            rank += (COLd[q][s2] == T && COLi[q][s2] < idx);
          if (rank < need) op[o++] = idx;
        }
      }
    }
  }
}

// ================= f32 GEMM (unchanged) =================
__global__ __launch_bounds__(128) void gemm_kernel(const float* __restrict__ In,
                                                   const float* __restrict__ W,
                                                   const float* __restrict__ bias,
                                                   const float* __restrict__ res,
                                                   float* __restrict__ Out,
                                                   int trans_out)
{
  __shared__ float Xs[128][68];
  __shared__ float Ws[16][68];
  const int b = blockIdx.z, c0 = blockIdx.y * 64, n0 = blockIdx.x * 64;
  const int tid = threadIdx.x;
  const int tx = tid & 7, ty = tid >> 3;
  const float* Inb = In + (size_t)b * CC * NN;
  {
    int qq = tid & 15, r0 = tid >> 4;
#pragma unroll
    for (int i = 0; i < 16; ++i) {
      int j = r0 + i * 8;
      float4 v = *(const float4*)&Inb[(size_t)j * NN + n0 + qq * 4];
      *(float4*)&Xs[j][qq * 4] = v;
    }
  }
  __syncthreads();
  float acc[4][8];
#pragma unroll
  for (int i = 0; i < 4; ++i)
#pragma unroll
    for (int j = 0; j < 8; ++j) acc[i][j] = 0.f;

  for (int ch = 0; ch < 8; ++ch) {
    {
      int c = tid & 63, jh = tid >> 6;
      const float* wp = &W[(size_t)(c0 + c) * 128 + ch * 16 + jh * 8];
      float4 w0 = *(const float4*)wp;
      float4 w1 = *(const float4*)(wp + 4);
      int r = jh * 8;
      Ws[r + 0][c] = w0.x; Ws[r + 1][c] = w0.y; Ws[r + 2][c] = w0.z; Ws[r + 3][c] = w0.w;
      Ws[r + 4][c] = w1.x; Ws[r + 5][c] = w1.y; Ws[r + 6][c] = w1.z; Ws[r + 7][c] = w1.w;
    }
    __syncthreads();
#pragma unroll
    for (int jj = 0; jj < 16; ++jj) {
      float4 a  = *(const float4*)&Ws[jj][ty * 4];
      float4 b0 = *(const float4*)&Xs[ch * 16 + jj][tx * 8];
      float4 b1 = *(const float4*)&Xs[ch * 16 + jj][tx * 8 + 4];
      float av[4]  = {a.x, a.y, a.z, a.w};
      float b0v[4] = {b0.x, b0.y, b0.z, b0.w};
      float b1v[4] = {b1.x, b1.y, b1.z, b1.w};
#pragma unroll
      for (int i = 0; i < 4; ++i)
#pragma unroll
        for (int j = 0; j < 4; ++j) {
          acc[i][j]     += av[i] * b0v[j];
          acc[i][j + 4] += av[i] * b1v[j];
        }
    }
    __syncthreads();
  }
  float4 bs = *(const float4*)&bias[c0 + ty * 4];
  float bv[4] = {bs.x, bs.y, bs.z, bs.w};
#pragma unroll
  for (int i = 0; i < 4; ++i)
#pragma unroll
    for (int j = 0; j < 8; ++j) acc[i][j] += bv[i];
  if (res) {
#pragma unroll
    for (int i = 0; i < 4; ++i) {
      const float* rp = &res[((size_t)b * CC + c0 + ty * 4 + i) * NN + n0 + tx * 8];
      float4 r0 = *(const float4*)rp;
      float4 r1 = *(const float4*)(rp + 4);
      acc[i][0] += r0.x; acc[i][1] += r0.y; acc[i][2] += r0.z; acc[i][3] += r0.w;
      acc[i][4] += r1.x; acc[i][5] += r1.y; acc[i][6] += r1.z; acc[i][7] += r1.w;
    }
  }
  if (trans_out) {
#pragma unroll
    for (int j = 0; j < 8; ++j) {
      float4 v = make_float4(acc[0][j], acc[1][j], acc[2][j], acc[3][j]);
      *(float4*)&Out[((size_t)b * NN + n0 + tx * 8 + j) * CC + c0 + ty * 4] = v;
    }
  } else {
#pragma unroll
    for (int i = 0; i < 4; ++i) {
      float* outp = &Out[((size_t)b * CC + c0 + ty * 4 + i) * NN + n0 + tx * 8];
      *(float4*)outp       = make_float4(acc[i][0], acc[i][1], acc[i][2], acc[i][3]);
      *(float4*)(outp + 4) = make_float4(acc[i][4], acc[i][5], acc[i][6], acc[i][7]);
    }
  }
}

// ================= Fused core, MFMA version ===========================================
// 8 points/block -> 128 cols (col = pt*16 + k); 4 waves; wave w owns C-rows [32w,32w+32).
// acts transposed in LDS: act[hi/lo][col][c] bf16; double-bf16 activations, bf16 weights.
#define TNP 8
__global__ __launch_bounds__(256, 2) void fused_kernel(
    const float* __restrict__ p, const int* __restrict__ idxg,
    const float* __restrict__ phi_t, const float* __restrict__ psi_t,
    const float* __restrict__ alp_t, const unsigned short* __restrict__ wpk,
    const float* __restrict__ d1W, const float* __restrict__ d1b,
    const float* __restrict__ d2b, const float* __restrict__ g1b,
    const float* __restrict__ g2b,
    float* __restrict__ y)
{
  __shared__ __align__(16) unsigned short act[2][128][136];  // [hi/lo][col][c], 272B rows
  __shared__ int idxs[128];
  const int b = blockIdx.y;
  const int n0 = blockIdx.x * TNP;
  const int tid = threadIdx.x;
  const int l = tid & 63;
  const int w = tid >> 6;
  const int lr = l & 15;        // fragment row/col lane
  const int lh = l >> 4;        // quarter-group

  if (tid < 128)
    idxs[tid] = idxg[((size_t)b * NN + n0 + (tid >> 4)) * KK + (tid & 15)];
  __syncthreads();

  // ---------- stage 0: rel -> pos1 = relu(d1W rel + d1b), hi/lo into act ----------
  {
    const int col = tid & 127, half = tid >> 7;
    const int pt = col >> 4;
    const int j = idxs[col];
    const float* pb = p + (size_t)b * 3 * NN;
    float r0 = pb[n0 + pt] - pb[j];
    float r1 = pb[NN + n0 + pt] - pb[NN + j];
    float r2 = pb[2 * NN + n0 + pt] - pb[2 * NN + j];
#pragma unroll
    for (int ch = 0; ch < 8; ++ch) {
      int c0 = half * 64 + ch * 8;
      short8v hv, lv;
#pragma unroll
      for (int e = 0; e < 8; ++e) {
        int c = c0 + e;
        float v = fmaxf(d1W[c * 3 + 0] * r0 + d1W[c * 3 + 1] * r1 + d1W[c * 3 + 2] * r2 + d1b[c], 0.f);
        unsigned short h = f2b(v);
        hv[e] = (short)h;
        lv[e] = (short)f2b(v - b2f(h));
      }
      *(short8v*)&act[0][col][c0] = hv;
      *(short8v*)&act[1][col][c0] = lv;
    }
  }
  __syncthreads();

  int idxv[8];
#pragma unroll
  for (int colt = 0; colt < 8; ++colt) idxv[colt] = idxs[colt * 16 + lr];

  f32x4 acc[2][8];
  short8v Af[2][4];

#define LOADA(MAT) do {                                                               \
  _Pragma("unroll") for (int ct = 0; ct < 2; ++ct)                                    \
    _Pragma("unroll") for (int ks = 0; ks < 4; ++ks)                                  \
      Af[ct][ks] = *(const short8v*)&wpk[(((((MAT)*8 + (2*w + ct))*4 + ks)*64) + l) * 8]; \
  } while (0)

#define MMUL() do {                                                                   \
  _Pragma("unroll") for (int ct = 0; ct < 2; ++ct)                                    \
    _Pragma("unroll") for (int colt = 0; colt < 8; ++colt)                            \
      acc[ct][colt] = (f32x4){0.f, 0.f, 0.f, 0.f};                                    \
  _Pragma("unroll") for (int colt = 0; colt < 8; ++colt) {                            \
    short8v Bh[4], Bl[4];                                                             \
    _Pragma("unroll") for (int ks = 0; ks < 4; ++ks) {                                \
      Bh[ks] = *(const short8v*)&act[0][colt * 16 + lr][ks * 32 + lh * 8];            \
      Bl[ks] = *(const short8v*)&act[1][colt * 16 + lr][ks * 32 + lh * 8];            \
    }                                                                                 \
    _Pragma("unroll") for (int ct = 0; ct < 2; ++ct)                                  \
      _Pragma("unroll") for (int ks = 0; ks < 4; ++ks) {                              \
        acc[ct][colt] = __builtin_amdgcn_mfma_f32_16x16x32_bf16(Af[ct][ks], Bh[ks],   \
                                                                acc[ct][colt], 0, 0, 0); \
        acc[ct][colt] = __builtin_amdgcn_mfma_f32_16x16x32_bf16(Af[ct][ks], Bl[ks],   \
                                                                acc[ct][colt], 0, 0, 0); \
      }                                                                               \
  } } while (0)

  // ---------- d2: pos = d2W @ pos1 + d2b (kept in registers) ----------
  LOADA(0); MMUL();
  float pos[2][8][4];
#pragma unroll
  for (int ct = 0; ct < 2; ++ct) {
    f32x4 bv = *(const f32x4*)&d2b[32 * w + ct * 16 + lh * 4];
#pragma unroll
    for (int colt = 0; colt < 8; ++colt)
#pragma unroll
      for (int r = 0; r < 4; ++r) pos[ct][colt][r] = acc[ct][colt][r] + bv[r];
  }
  __syncthreads();   // all waves done reading pos1

  // ---------- ain = pos + phi[n] - psi[idx]  -> act ----------
#pragma unroll
  for (int colt = 0; colt < 8; ++colt) {
    size_t prow = ((size_t)b * NN + n0 + colt) * CC;
    size_t srow = ((size_t)b * NN + idxv[colt]) * CC;
#pragma unroll
    for (int ct = 0; ct < 2; ++ct) {
      int c0 = 32 * w + ct * 16 + lh * 4;
      f32x4 ph = *(const f32x4*)&phi_t[prow + c0];
      f32x4 ps = *(const f32x4*)&psi_t[srow + c0];
      short4v hq, lq;
#pragma unroll
      for (int r = 0; r < 4; ++r) {
        float v = pos[ct][colt][r] + ph[r] - ps[r];
        unsigned short h = f2b(v);
        hq[r] = (short)h;
        lq[r] = (short)f2b(v - b2f(h));
      }
      *(short4v*)&act[0][colt * 16 + lr][c0] = hq;
      *(short4v*)&act[1][colt * 16 + lr][c0] = lq;
    }
  }
  __syncthreads();

  // ---------- g1: h = relu(g1W @ ain + g1b) -> act ----------
  LOADA(1); MMUL();
  __syncthreads();   // all waves done reading ain
#pragma unroll
  for (int ct = 0; ct < 2; ++ct) {
    f32x4 bv = *(const f32x4*)&g1b[32 * w + ct * 16 + lh * 4];
    int c0 = 32 * w + ct * 16 + lh * 4;
#pragma unroll
    for (int colt = 0; colt < 8; ++colt) {
      short4v hq, lq;
#pragma unroll
      for (int r = 0; r < 4; ++r) {
        float v = fmaxf(acc[ct][colt][r] + bv[r], 0.f);
        unsigned short h = f2b(v);
        hq[r] = (short)h;
        lq[r] = (short)f2b(v - b2f(h));
      }
      *(short4v*)&act[0][colt * 16 + lr][c0] = hq;
      *(short4v*)&act[1][colt * 16 + lr][c0] = lq;
    }
  }
  __syncthreads();

  // ---------- g2: attn = g2W @ h + g2b ----------
  LOADA(2); MMUL();
#pragma unroll
  for (int ct = 0; ct < 2; ++ct) {
    f32x4 bv = *(const f32x4*)&g2b[32 * w + ct * 16 + lh * 4];
#pragma unroll
    for (int colt = 0; colt < 8; ++colt)
#pragma unroll
      for (int r = 0; r < 4; ++r) acc[ct][colt][r] += bv[r];
  }

  // ---------- softmax over k (= lr lanes within each colt) ----------
#pragma unroll
  for (int ct = 0; ct < 2; ++ct)
#pragma unroll
    for (int colt = 0; colt < 8; ++colt)
#pragma unroll
      for (int r = 0; r < 4; ++r) {
        float a = acc[ct][colt][r];
        float m = a;
        m = fmaxf(m, __shfl_xor(m, 1));
        m = fmaxf(m, __shfl_xor(m, 2));
        m = fmaxf(m, __shfl_xor(m, 4));
        m = fmaxf(m, __shfl_xor(m, 8));
        float e = __expf(a - m);
        float s = e;
        s += __shfl_xor(s, 1);
        s += __shfl_xor(s, 2);
        s += __shfl_xor(s, 4);
        s += __shfl_xor(s, 8);
        acc[ct][colt][r] = e / s;
      }

  // ---------- combine: y[c][n] = sum_k wgt * (alpha[idx] + pos) ----------
#pragma unroll
  for (int colt = 0; colt < 8; ++colt) {
    size_t arow = ((size_t)b * NN + idxv[colt]) * CC;
#pragma unroll
    for (int ct = 0; ct < 2; ++ct) {
      int c0 = 32 * w + ct * 16 + lh * 4;
      f32x4 av = *(const f32x4*)&alp_t[arow + c0];
#pragma unroll
      for (int r = 0; r < 4; ++r) {
        float part = acc[ct][colt][r] * (av[r] + pos[ct][colt][r]);
        part += __shfl_xor(part, 1);
        part += __shfl_xor(part, 2);
        part += __shfl_xor(part, 4);
        part += __shfl_xor(part, 8);
        if (lr == 0)
          y[((size_t)b * CC + c0 + r) * NN + n0 + colt] = part;
      }
    }
  }
#undef LOADA
#undef MMUL
}

// =============================================================================================
extern "C" void kernel_launch(void* const* d_in, const int* in_sizes, int n_in,
                              void* d_out, int out_size, void* d_ws, size_t ws_size,
                              hipStream_t stream) {
  const float* input_p = (const float*)d_in[0];
  const float* input_x = (const float*)d_in[1];
  const float* top_W   = (const float*)d_in[2];  const float* top_b   = (const float*)d_in[3];
  const float* down_W  = (const float*)d_in[4];  const float* down_b  = (const float*)d_in[5];
  const float* phi_W   = (const float*)d_in[6];  const float* phi_b   = (const float*)d_in[7];
  const float* psi_W   = (const float*)d_in[8];  const float* psi_b   = (const float*)d_in[9];
  const float* alpha_W = (const float*)d_in[10]; const float* alpha_b = (const float*)d_in[11];
  const float* g1_W    = (const float*)d_in[12]; const float* g1_b    = (const float*)d_in[13];
  const float* g2_W    = (const float*)d_in[14]; const float* g2_b    = (const float*)d_in[15];
  const float* d1_W    = (const float*)d_in[16]; const float* d1_b    = (const float*)d_in[17];
  const float* d2_W    = (const float*)d_in[18]; const float* d2_b    = (const float*)d_in[19];
  float* out = (float*)d_out;

  char* ws = (char*)d_ws;
  int*    ws_idx = (int*)ws;                               // 1 MB: [B][N][16]
  float*  ws_x   = (float*)(ws + (size_t)1 * (1 << 20));   // 8 MB: [B][C][N]
  float*  ws_phi = (float*)(ws + (size_t)9 * (1 << 20));   // 8 MB: [B][N][C]
  float*  ws_psi = (float*)(ws + (size_t)17 * (1 << 20));  // 8 MB: [B][N][C]
  float*  ws_alp = (float*)(ws + (size_t)25 * (1 << 20));  // 8 MB: [B][N][C]
  float*  ws_y   = (float*)(ws + (size_t)33 * (1 << 20));  // 8 MB: [B][C][N]
  float4* ws_pkg = (float4*)(ws + (size_t)41 * (1 << 20)); // 256 KB
  unsigned short* ws_wpk = (unsigned short*)(ws + (size_t)41 * (1 << 20) + (1 << 18)); // 96 KB

  prep_kernel<<<(BB * NN) / 256, 256, 0, stream>>>(input_p, ws_pkg);
  wprep_kernel<<<24, 256, 0, stream>>>(d2_W, g1_W, g2_W, ws_wpk);
  knn_kernel<<<dim3(NN / 64, BB), 512, 0, stream>>>(ws_pkg, ws_idx);
  gemm_kernel<<<dim3(NN / 64, 2, BB), 128, 0, stream>>>(input_x, top_W, top_b, nullptr, ws_x, 0);
  gemm_kernel<<<dim3(NN / 64, 2, BB), 128, 0, stream>>>(ws_x, phi_W, phi_b, nullptr, ws_phi, 1);
  gemm_kernel<<<dim3(NN / 64, 2, BB), 128, 0, stream>>>(ws_x, psi_W, psi_b, nullptr, ws_psi, 1);
  gemm_kernel<<<dim3(NN / 64, 2, BB), 128, 0, stream>>>(ws_x, alpha_W, alpha_b, nullptr, ws_alp, 1);
  fused_kernel<<<dim3(NN / TNP, BB), 256, 0, stream>>>(input_p, ws_idx, ws_phi, ws_psi, ws_alp,
                                                       ws_wpk, d1_W, d1_b, d2_b, g1_b, g2_b, ws_y);
  gemm_kernel<<<dim3(NN / 64, 2, BB), 128, 0, stream>>>(ws_y, down_W, down_b, input_x, out, 0);
}

// Round 5
// 394.401 us; speedup vs baseline: 2.8942x; 1.2563x over previous
//
#include <hip/hip_runtime.h>
#include <hip/hip_bf16.h>

#define BB 4
#define CC 128
#define NN 4096
#define KK 16
#define FLT_BIG 3.402823466e+38f

typedef __attribute__((ext_vector_type(8))) short short8v;
typedef __attribute__((ext_vector_type(4))) short short4v;
typedef __attribute__((ext_vector_type(4))) float f32x4;

__device__ __forceinline__ unsigned short f2b(float x) {   // RNE f32->bf16
  union { float f; unsigned u; } v; v.f = x;
  unsigned r = v.u + 0x7fffu + ((v.u >> 16) & 1u);
  return (unsigned short)(r >> 16);
}
__device__ __forceinline__ float b2f(unsigned short h) {
  union { float f; unsigned u; } v; v.u = ((unsigned)h) << 16; return v.f;
}

// ---- shared distance: identical instruction sequence everywhere (bit-exact re-eval) ----
__device__ __forceinline__ float dist4(const float4 q, const float4 c) {
  float t = __fmaf_rn(q.x, c.x, __fmaf_rn(q.y, c.y, __fmul_rn(q.z, c.z)));
  return __fmaf_rn(-2.f, t, q.w + c.w);
}

// ================= prep: pack p -> (x,y,z,|p|^2) float4 =================
__global__ __launch_bounds__(256) void prep_kernel(const float* __restrict__ p,
                                                   float4* __restrict__ pkg) {
  int i = blockIdx.x * 256 + threadIdx.x;   // 0..B*N-1
  int b = i >> 12, m = i & (NN - 1);
  const float* pb = p + (size_t)b * 3 * NN;
  float x = pb[m], y = pb[NN + m], z = pb[2 * NN + m];
  pkg[i] = make_float4(x, y, z, __fmaf_rn(x, x, __fmaf_rn(y, y, __fmul_rn(z, z))));
}

// ================= wprep: pack 8 weight mats into bf16-pair MFMA fragment layout =========
// wpk[mat(8)][hl(2)][ct(8)][ks(4)][lane(64)][8] halfwords; elem j = W[ct*16+(l&15)][ks*32+(l>>4)*8+j]
// mats: 0=d2 1=g1 2=g2 3=top 4=phi 5=psi 6=alpha 7=down
__global__ __launch_bounds__(256) void wprep_kernel(
    const float* __restrict__ d2W, const float* __restrict__ g1W,
    const float* __restrict__ g2W, const float* __restrict__ topW,
    const float* __restrict__ phiW, const float* __restrict__ psiW,
    const float* __restrict__ alpW, const float* __restrict__ dnW,
    unsigned short* __restrict__ wpk) {
  int t = blockIdx.x * 256 + threadIdx.x;         // 0..16383
  int mat = t >> 11, r = t & 2047;
  int ct = r >> 8, ks = (r >> 6) & 3, lane = r & 63;
  const float* W;
  switch (mat) {
    case 0: W = d2W; break;  case 1: W = g1W; break;
    case 2: W = g2W; break;  case 3: W = topW; break;
    case 4: W = phiW; break; case 5: W = psiW; break;
    case 6: W = alpW; break; default: W = dnW; break;
  }
  int row = ct * 16 + (lane & 15);
  int k0 = ks * 32 + (lane >> 4) * 8;
  const float* src = &W[row * 128 + k0];
  unsigned short* dh = &wpk[((size_t)(((mat * 2 + 0) * 8 + ct) * 4 + ks) * 64 + lane) * 8];
  unsigned short* dl = &wpk[((size_t)(((mat * 2 + 1) * 8 + ct) * 4 + ks) * 64 + lane) * 8];
#pragma unroll
  for (int e = 0; e < 8; ++e) {
    float v = src[e];
    unsigned short h = f2b(v);
    dh[e] = h;
    dl[e] = f2b(v - b2f(h));
  }
}

// ================= xpose: input_x [B][C][N] f32 -> xin hi/lo bf16 planes [B][N][C] =========
__global__ __launch_bounds__(256) void xpose_kernel(const float* __restrict__ x,
                                                    unsigned short* __restrict__ xh,
                                                    unsigned short* __restrict__ xl) {
  __shared__ float t[64][65];
  const int b = blockIdx.z, c0 = blockIdx.y * 64, n0 = blockIdx.x * 64;
  const int tn = threadIdx.x & 63, tq = threadIdx.x >> 6;
  const float* xb = x + ((size_t)b * CC + c0) * NN + n0;
#pragma unroll
  for (int i = 0; i < 16; ++i) {
    int c = tq * 16 + i;
    t[c][tn] = xb[(size_t)c * NN + tn];
  }
  __syncthreads();
#pragma unroll
  for (int i = 0; i < 16; ++i) {
    int nl = tq * 16 + i;
    float v = t[tn][nl];
    unsigned short h = f2b(v);
    size_t o = ((size_t)b * NN + n0 + nl) * CC + c0 + tn;
    xh[o] = h;
    xl[o] = f2b(v - b2f(h));
  }
}

// ================= KNN: exact 16-NN set (order-free; boundary ties -> lowest index) ======
__global__ __launch_bounds__(512, 2) void knn_kernel(const float4* __restrict__ pkg,
                                                     int* __restrict__ outidx)
{
  __shared__ float BD[8][64][17];
  __shared__ float TS[64];
  __shared__ int   CNT[64];
  __shared__ float COLd[64][20];
  __shared__ int   COLi[64][20];
  const int b = blockIdx.y;
  const int tid = threadIdx.x;
  const int lane = tid & 63;
  const int w = tid >> 6;
  const int n = blockIdx.x * 64 + lane;
  const float4* PB = pkg + (size_t)b * NN;
  const float4 qc = PB[n];
  if (tid < 64) CNT[tid] = 0;

  float bd[16];
#pragma unroll
  for (int t = 0; t < 16; ++t) bd[t] = FLT_BIG;
  const int m0 = w * 512;
#pragma unroll 4
  for (int m = m0; m < m0 + 512; ++m) {
    float4 c = PB[m];
    float d = dist4(qc, c);
#pragma unroll
    for (int t = 15; t >= 1; --t) bd[t] = __builtin_amdgcn_fmed3f(bd[t - 1], d, bd[t]);
    bd[0] = fminf(bd[0], d);
  }
#pragma unroll
  for (int t = 0; t < 16; ++t) BD[w][lane][t] = bd[t];
  __syncthreads();

  if (tid < 64) {
    const int q = tid;
    int h0 = 0, h1 = 0, h2 = 0, h3 = 0, h4 = 0, h5 = 0, h6 = 0, h7 = 0;
    float mv = FLT_BIG;
#pragma unroll 1
    for (int r = 0; r < 16; ++r) {
      float v0 = BD[0][q][h0], v1 = BD[1][q][h1], v2 = BD[2][q][h2], v3 = BD[3][q][h3];
      float v4 = BD[4][q][h4], v5 = BD[5][q][h5], v6 = BD[6][q][h6], v7 = BD[7][q][h7];
      mv = v0; int mw = 0;
      if (v1 < mv) { mv = v1; mw = 1; }
      if (v2 < mv) { mv = v2; mw = 2; }
      if (v3 < mv) { mv = v3; mw = 3; }
      if (v4 < mv) { mv = v4; mw = 4; }
      if (v5 < mv) { mv = v5; mw = 5; }
      if (v6 < mv) { mv = v6; mw = 6; }
      if (v7 < mv) { mv = v7; mw = 7; }
      h0 += (mw == 0); h1 += (mw == 1); h2 += (mw == 2); h3 += (mw == 3);
      h4 += (mw == 4); h5 += (mw == 5); h6 += (mw == 6); h7 += (mw == 7);
    }
    TS[q] = mv;
  }
  __syncthreads();

  {
    const float thr = TS[lane];
#pragma unroll 4
    for (int m = m0; m < m0 + 512; ++m) {
      float4 c = PB[m];
      float d = dist4(qc, c);
      if (d <= thr) {
        int pos = atomicAdd(&CNT[lane], 1);
        if (pos < 20) { COLd[lane][pos] = d; COLi[lane][pos] = m; }
      }
    }
  }
  __syncthreads();

  if (tid < 64) {
    const int q = tid;
    int c = CNT[q]; if (c > 20) c = 20;
    int* op = outidx + ((size_t)b * NN + blockIdx.x * 64 + q) * KK;
    if (c == KK) {
#pragma unroll
      for (int o = 0; o < KK; ++o) op[o] = COLi[q][o];
    } else {
      const float T = TS[q];
      int less = 0;
      for (int s = 0; s < c; ++s) less += (COLd[q][s] < T);
      int need = KK - less;
      int o = 0;
      for (int s = 0; s < c; ++s)
        if (COLd[q][s] < T) op[o++] = COLi[q][s];
      for (int s = 0; s < c; ++s) {
        if (COLd[q][s] == T) {
          int idx = COLi[q][s];
          int rank = 0;
          for (int s2 = 0; s2 < c; ++s2)
            rank += (COLd[q][s2] == T && COLi[q][s2] < idx);
          if (rank < need) op[o++] = idx;
        }
      }
    }
  }
}

// ================= top: x^T = xin^T @ topW^T + b  (pair-plane output) ====================
// block 256 = 4 waves; block tile 32n x 128c; wave: nt=w&1 (16 rows), cq=w>>1 (4 colt)
__global__ __launch_bounds__(256) void topgemm_kernel(
    const unsigned short* __restrict__ xh, const unsigned short* __restrict__ xl,
    const unsigned short* __restrict__ wpk, const float* __restrict__ bias,
    unsigned short* __restrict__ oh, unsigned short* __restrict__ ol)
{
  const int b = blockIdx.y, n0 = blockIdx.x * 32;
  const int tid = threadIdx.x, l = tid & 63, w = tid >> 6;
  const int lr = l & 15, lh = l >> 4;
  const int nt = w & 1, cq = w >> 1;
  const int nrow = n0 + nt * 16 + lr;
  const unsigned short* xhp = xh + ((size_t)b * NN + nrow) * CC;
  const unsigned short* xlp = xl + ((size_t)b * NN + nrow) * CC;
  short8v Ah[4], Al[4];
#pragma unroll
  for (int ks = 0; ks < 4; ++ks) {
    Ah[ks] = *(const short8v*)&xhp[ks * 32 + lh * 8];
    Al[ks] = *(const short8v*)&xlp[ks * 32 + lh * 8];
  }
  const int nD = n0 + nt * 16 + lh * 4;
#pragma unroll
  for (int cc = 0; cc < 4; ++cc) {
    const int colt = cq * 4 + cc;
    f32x4 acc = (f32x4){0.f, 0.f, 0.f, 0.f};
#pragma unroll
    for (int ks = 0; ks < 4; ++ks) {
      short8v Wh = *(const short8v*)&wpk[((size_t)(((3 * 2 + 0) * 8 + colt) * 4 + ks) * 64 + l) * 8];
      short8v Wl = *(const short8v*)&wpk[((size_t)(((3 * 2 + 1) * 8 + colt) * 4 + ks) * 64 + l) * 8];
      acc = __builtin_amdgcn_mfma_f32_16x16x32_bf16(Ah[ks], Wh, acc, 0, 0, 0);
      acc = __builtin_amdgcn_mfma_f32_16x16x32_bf16(Al[ks], Wh, acc, 0, 0, 0);
      acc = __builtin_amdgcn_mfma_f32_16x16x32_bf16(Ah[ks], Wl, acc, 0, 0, 0);
    }
    float bv = bias[colt * 16 + lr];
#pragma unroll
    for (int r = 0; r < 4; ++r) {
      float v = acc[r] + bv;
      unsigned short h = f2b(v);
      size_t o = ((size_t)b * NN + nD + r) * CC + colt * 16 + lr;
      oh[o] = h;
      ol[o] = f2b(v - b2f(h));
    }
  }
}

// ================= pqa: phi/psi/alpha = x^T @ W^T + b (f32 [B][N][C] outputs) ============
__global__ __launch_bounds__(256) void pqa_kernel(
    const unsigned short* __restrict__ xh, const unsigned short* __restrict__ xl,
    const unsigned short* __restrict__ wpk,
    const float* __restrict__ phib, const float* __restrict__ psib,
    const float* __restrict__ alpb,
    float* __restrict__ phit, float* __restrict__ psit, float* __restrict__ alpt)
{
  const int b = blockIdx.y, n0 = blockIdx.x * 32;
  const int tid = threadIdx.x, l = tid & 63, w = tid >> 6;
  const int lr = l & 15, lh = l >> 4;
  const int nt = w & 1, cq = w >> 1;
  const int nrow = n0 + nt * 16 + lr;
  const unsigned short* xhp = xh + ((size_t)b * NN + nrow) * CC;
  const unsigned short* xlp = xl + ((size_t)b * NN + nrow) * CC;
  short8v Ah[4], Al[4];
#pragma unroll
  for (int ks = 0; ks < 4; ++ks) {
    Ah[ks] = *(const short8v*)&xhp[ks * 32 + lh * 8];
    Al[ks] = *(const short8v*)&xlp[ks * 32 + lh * 8];
  }
  const int nD = n0 + nt * 16 + lh * 4;
#pragma unroll
  for (int m = 0; m < 3; ++m) {
    const int mat = 4 + m;
    const float* bias = (m == 0) ? phib : (m == 1) ? psib : alpb;
    float* outp = (m == 0) ? phit : (m == 1) ? psit : alpt;
#pragma unroll
    for (int cc = 0; cc < 4; ++cc) {
      const int colt = cq * 4 + cc;
      f32x4 acc = (f32x4){0.f, 0.f, 0.f, 0.f};
#pragma unroll
      for (int ks = 0; ks < 4; ++ks) {
        short8v Wh = *(const short8v*)&wpk[((size_t)(((mat * 2 + 0) * 8 + colt) * 4 + ks) * 64 + l) * 8];
        short8v Wl = *(const short8v*)&wpk[((size_t)(((mat * 2 + 1) * 8 + colt) * 4 + ks) * 64 + l) * 8];
        acc = __builtin_amdgcn_mfma_f32_16x16x32_bf16(Ah[ks], Wh, acc, 0, 0, 0);
        acc = __builtin_amdgcn_mfma_f32_16x16x32_bf16(Al[ks], Wh, acc, 0, 0, 0);
        acc = __builtin_amdgcn_mfma_f32_16x16x32_bf16(Ah[ks], Wl, acc, 0, 0, 0);
      }
      float bv = bias[colt * 16 + lr];
#pragma unroll
      for (int r = 0; r < 4; ++r)
        outp[((size_t)b * NN + nD + r) * CC + colt * 16 + lr] = acc[r] + bv;
    }
  }
}

// ================= down: out = dnW @ y + b + res  (y from pair planes) ==================
// block 256 = 4 waves; tile 128c x 64n; wave w: c rows [32w,32w+32), colt 0..3
__global__ __launch_bounds__(256) void down_kernel(
    const unsigned short* __restrict__ yh, const unsigned short* __restrict__ yl,
    const unsigned short* __restrict__ wpk,
    const float* __restrict__ bias, const float* __restrict__ res,
    float* __restrict__ out)
{
  const int b = blockIdx.y, n0 = blockIdx.x * 64;
  const int tid = threadIdx.x, l = tid & 63, w = tid >> 6;
  const int lr = l & 15, lh = l >> 4;
  short8v Ah[2][4], Al[2][4];
#pragma unroll
  for (int ct = 0; ct < 2; ++ct)
#pragma unroll
    for (int ks = 0; ks < 4; ++ks) {
      Ah[ct][ks] = *(const short8v*)&wpk[((size_t)(((7 * 2 + 0) * 8 + (2 * w + ct)) * 4 + ks) * 64 + l) * 8];
      Al[ct][ks] = *(const short8v*)&wpk[((size_t)(((7 * 2 + 1) * 8 + (2 * w + ct)) * 4 + ks) * 64 + l) * 8];
    }
  f32x4 acc[2][4];
#pragma unroll
  for (int colt = 0; colt < 4; ++colt) {
    const int n = n0 + colt * 16 + lr;
    const unsigned short* yhp = yh + ((size_t)b * NN + n) * CC;
    const unsigned short* ylp = yl + ((size_t)b * NN + n) * CC;
#pragma unroll
    for (int ct = 0; ct < 2; ++ct) acc[ct][colt] = (f32x4){0.f, 0.f, 0.f, 0.f};
#pragma unroll
    for (int ks = 0; ks < 4; ++ks) {
      short8v Bh = *(const short8v*)&yhp[ks * 32 + lh * 8];
      short8v Bl = *(const short8v*)&ylp[ks * 32 + lh * 8];
#pragma unroll
      for (int ct = 0; ct < 2; ++ct) {
        acc[ct][colt] = __builtin_amdgcn_mfma_f32_16x16x32_bf16(Ah[ct][ks], Bh, acc[ct][colt], 0, 0, 0);
        acc[ct][colt] = __builtin_amdgcn_mfma_f32_16x16x32_bf16(Ah[ct][ks], Bl, acc[ct][colt], 0, 0, 0);
        acc[ct][colt] = __builtin_amdgcn_mfma_f32_16x16x32_bf16(Al[ct][ks], Bh, acc[ct][colt], 0, 0, 0);
      }
    }
  }
#pragma unroll
  for (int ct = 0; ct < 2; ++ct) {
    const int c0 = 32 * w + ct * 16 + lh * 4;
#pragma unroll
    for (int r = 0; r < 4; ++r) {
      float bv = bias[c0 + r];
#pragma unroll
      for (int colt = 0; colt < 4; ++colt) {
        size_t o = ((size_t)b * CC + c0 + r) * NN + n0 + colt * 16 + lr;
        out[o] = acc[ct][colt][r] + bv + res[o];
      }
    }
  }
}

// ================= Fused core, MFMA, TNP=4 (35 KB LDS -> 4 blocks/CU) =====================
#define TNP 4
__global__ __launch_bounds__(256, 4) void fused_kernel(
    const float* __restrict__ p, const int* __restrict__ idxg,
    const float* __restrict__ phi_t, const float* __restrict__ psi_t,
    const float* __restrict__ alp_t, const unsigned short* __restrict__ wpk,
    const float* __restrict__ d1W, const float* __restrict__ d1b,
    const float* __restrict__ d2b, const float* __restrict__ g1b,
    const float* __restrict__ g2b,
    unsigned short* __restrict__ yh, unsigned short* __restrict__ yl)
{
  __shared__ __align__(16) unsigned short act[2][64][136];  // [hi/lo][col][c]
  __shared__ int idxs[64];
  const int b = blockIdx.y;
  const int n0 = blockIdx.x * TNP;
  const int tid = threadIdx.x;
  const int l = tid & 63, w = tid >> 6;
  const int lr = l & 15, lh = l >> 4;

  if (tid < 64) idxs[tid] = idxg[((size_t)b * NN + n0 + (tid >> 4)) * KK + (tid & 15)];
  __syncthreads();

  // ---------- stage 0: rel -> pos1 = relu(d1W rel + d1b), hi/lo into act ----------
  {
    const int col = tid & 63, q = tid >> 6;
    const int pt = col >> 4;
    const int j = idxs[col];
    const float* pb = p + (size_t)b * 3 * NN;
    float r0 = pb[n0 + pt] - pb[j];
    float r1 = pb[NN + n0 + pt] - pb[NN + j];
    float r2 = pb[2 * NN + n0 + pt] - pb[2 * NN + j];
#pragma unroll
    for (int ch = 0; ch < 4; ++ch) {
      int c0 = q * 32 + ch * 8;
      short8v hv, lv;
#pragma unroll
      for (int e = 0; e < 8; ++e) {
        int c = c0 + e;
        float v = fmaxf(d1W[c * 3 + 0] * r0 + d1W[c * 3 + 1] * r1 + d1W[c * 3 + 2] * r2 + d1b[c], 0.f);
        unsigned short h = f2b(v);
        hv[e] = (short)h;
        lv[e] = (short)f2b(v - b2f(h));
      }
      *(short8v*)&act[0][col][c0] = hv;
      *(short8v*)&act[1][col][c0] = lv;
    }
  }
  __syncthreads();

  int idxv[TNP];
#pragma unroll
  for (int colt = 0; colt < TNP; ++colt) idxv[colt] = idxs[colt * 16 + lr];

  f32x4 acc[2][TNP];
  short8v Af[2][4];

#define LOADA(MAT) do {                                                                 \
  _Pragma("unroll") for (int ct = 0; ct < 2; ++ct)                                      \
    _Pragma("unroll") for (int ks = 0; ks < 4; ++ks)                                    \
      Af[ct][ks] = *(const short8v*)&wpk[((size_t)((((MAT) * 2 + 0) * 8 + (2 * w + ct)) * 4 + ks) * 64 + l) * 8]; \
  } while (0)

#define MMUL() do {                                                                     \
  _Pragma("unroll") for (int ct = 0; ct < 2; ++ct)                                      \
    _Pragma("unroll") for (int colt = 0; colt < TNP; ++colt)                            \
      acc[ct][colt] = (f32x4){0.f, 0.f, 0.f, 0.f};                                      \
  _Pragma("unroll") for (int colt = 0; colt < TNP; ++colt) {                            \
    short8v Bh[4], Bl[4];                                                               \
    _Pragma("unroll") for (int ks = 0; ks < 4; ++ks) {                                  \
      Bh[ks] = *(const short8v*)&act[0][colt * 16 + lr][ks * 32 + lh * 8];              \
      Bl[ks] = *(const short8v*)&act[1][colt * 16 + lr][ks * 32 + lh * 8];              \
    }                                                                                   \
    _Pragma("unroll") for (int ct = 0; ct < 2; ++ct)                                    \
      _Pragma("unroll") for (int ks = 0; ks < 4; ++ks) {                                \
        acc[ct][colt] = __builtin_amdgcn_mfma_f32_16x16x32_bf16(Af[ct][ks], Bh[ks],     \
                                                                acc[ct][colt], 0, 0, 0); \
        acc[ct][colt] = __builtin_amdgcn_mfma_f32_16x16x32_bf16(Af[ct][ks], Bl[ks],     \
                                                                acc[ct][colt], 0, 0, 0); \
      }                                                                                 \
  } } while (0)

  // ---------- d2: pos = d2W @ pos1 + d2b (kept in registers) ----------
  LOADA(0); MMUL();
  float pos[2][TNP][4];
#pragma unroll
  for (int ct = 0; ct < 2; ++ct) {
    f32x4 bv = *(const f32x4*)&d2b[32 * w + ct * 16 + lh * 4];
#pragma unroll
    for (int colt = 0; colt < TNP; ++colt)
#pragma unroll
      for (int r = 0; r < 4; ++r) pos[ct][colt][r] = acc[ct][colt][r] + bv[r];
  }
  __syncthreads();   // all waves done reading pos1

  // ---------- ain = pos + phi[n] - psi[idx] -> act ----------
#pragma unroll
  for (int colt = 0; colt < TNP; ++colt) {
    size_t prow = ((size_t)b * NN + n0 + colt) * CC;
    size_t srow = ((size_t)b * NN + idxv[colt]) * CC;
#pragma unroll
    for (int ct = 0; ct < 2; ++ct) {
      int c0 = 32 * w + ct * 16 + lh * 4;
      f32x4 ph = *(const f32x4*)&phi_t[prow + c0];
      f32x4 ps = *(const f32x4*)&psi_t[srow + c0];
      short4v hq, lq;
#pragma unroll
      for (int r = 0; r < 4; ++r) {
        float v = pos[ct][colt][r] + ph[r] - ps[r];
        unsigned short h = f2b(v);
        hq[r] = (short)h;
        lq[r] = (short)f2b(v - b2f(h));
      }
      *(short4v*)&act[0][colt * 16 + lr][c0] = hq;
      *(short4v*)&act[1][colt * 16 + lr][c0] = lq;
    }
  }
  __syncthreads();

  // ---------- g1: h = relu(g1W @ ain + g1b) -> act ----------
  LOADA(1); MMUL();
  __syncthreads();   // all waves done reading ain
#pragma unroll
  for (int ct = 0; ct < 2; ++ct) {
    f32x4 bv = *(const f32x4*)&g1b[32 * w + ct * 16 + lh * 4];
    int c0 = 32 * w + ct * 16 + lh * 4;
#pragma unroll
    for (int colt = 0; colt < TNP; ++colt) {
      short4v hq, lq;
#pragma unroll
      for (int r = 0; r < 4; ++r) {
        float v = fmaxf(acc[ct][colt][r] + bv[r], 0.f);
        unsigned short h = f2b(v);
        hq[r] = (short)h;
        lq[r] = (short)f2b(v - b2f(h));
      }
      *(short4v*)&act[0][colt * 16 + lr][c0] = hq;
      *(short4v*)&act[1][colt * 16 + lr][c0] = lq;
    }
  }
  __syncthreads();

  // ---------- g2: attn = g2W @ h + g2b ----------
  LOADA(2); MMUL();
#pragma unroll
  for (int ct = 0; ct < 2; ++ct) {
    f32x4 bv = *(const f32x4*)&g2b[32 * w + ct * 16 + lh * 4];
#pragma unroll
    for (int colt = 0; colt < TNP; ++colt)
#pragma unroll
      for (int r = 0; r < 4; ++r) acc[ct][colt][r] += bv[r];
  }

  // ---------- softmax over k (= lr lanes within each colt) ----------
#pragma unroll
  for (int ct = 0; ct < 2; ++ct)
#pragma unroll
    for (int colt = 0; colt < TNP; ++colt)
#pragma unroll
      for (int r = 0; r < 4; ++r) {
        float a = acc[ct][colt][r];
        float m = a;
        m = fmaxf(m, __shfl_xor(m, 1));
        m = fmaxf(m, __shfl_xor(m, 2));
        m = fmaxf(m, __shfl_xor(m, 4));
        m = fmaxf(m, __shfl_xor(m, 8));
        float e = __expf(a - m);
        float s = e;
        s += __shfl_xor(s, 1);
        s += __shfl_xor(s, 2);
        s += __shfl_xor(s, 4);
        s += __shfl_xor(s, 8);
        acc[ct][colt][r] = e / s;
      }

  // ---------- combine: y_t[n][c] = sum_k wgt * (alpha[idx] + pos), bf16-pair out ----------
#pragma unroll
  for (int colt = 0; colt < TNP; ++colt) {
    size_t arow = ((size_t)b * NN + idxv[colt]) * CC;
#pragma unroll
    for (int ct = 0; ct < 2; ++ct) {
      int c0 = 32 * w + ct * 16 + lh * 4;
      f32x4 av = *(const f32x4*)&alp_t[arow + c0];
      f32x4 yv;
#pragma unroll
      for (int r = 0; r < 4; ++r) {
        float part = acc[ct][colt][r] * (av[r] + pos[ct][colt][r]);
        part += __shfl_xor(part, 1);
        part += __shfl_xor(part, 2);
        part += __shfl_xor(part, 4);
        part += __shfl_xor(part, 8);
        yv[r] = part;
      }
      if (lr == 0) {
        short4v hq, lq;
#pragma unroll
        for (int r = 0; r < 4; ++r) {
          unsigned short h = f2b(yv[r]);
          hq[r] = (short)h;
          lq[r] = (short)f2b(yv[r] - b2f(h));
        }
        size_t o = ((size_t)b * NN + n0 + colt) * CC + c0;
        *(short4v*)&yh[o] = hq;
        *(short4v*)&yl[o] = lq;
      }
    }
  }
#undef LOADA
#undef MMUL
}

// =============================================================================================
extern "C" void kernel_launch(void* const* d_in, const int* in_sizes, int n_in,
                              void* d_out, int out_size, void* d_ws, size_t ws_size,
                              hipStream_t stream) {
  const float* input_p = (const float*)d_in[0];
  const float* input_x = (const float*)d_in[1];
  const float* top_W   = (const float*)d_in[2];  const float* top_b   = (const float*)d_in[3];
  const float* down_W  = (const float*)d_in[4];  const float* down_b  = (const float*)d_in[5];
  const float* phi_W   = (const float*)d_in[6];  const float* phi_b   = (const float*)d_in[7];
  const float* psi_W   = (const float*)d_in[8];  const float* psi_b   = (const float*)d_in[9];
  const float* alpha_W = (const float*)d_in[10]; const float* alpha_b = (const float*)d_in[11];
  const float* g1_W    = (const float*)d_in[12]; const float* g1_b    = (const float*)d_in[13];
  const float* g2_W    = (const float*)d_in[14]; const float* g2_b    = (const float*)d_in[15];
  const float* d1_W    = (const float*)d_in[16]; const float* d1_b    = (const float*)d_in[17];
  const float* d2_W    = (const float*)d_in[18]; const float* d2_b    = (const float*)d_in[19];
  float* out = (float*)d_out;

  char* ws = (char*)d_ws;
  int*            ws_idx = (int*)ws;                                    // 1 MB
  unsigned short* ws_xin_h = (unsigned short*)(ws + (size_t)1  * (1 << 20)); // 4 MB (reused as y_h)
  unsigned short* ws_xin_l = (unsigned short*)(ws + (size_t)5  * (1 << 20)); // 4 MB (reused as y_l)
  unsigned short* ws_x_h   = (unsigned short*)(ws + (size_t)9  * (1 << 20)); // 4 MB
  unsigned short* ws_x_l   = (unsigned short*)(ws + (size_t)13 * (1 << 20)); // 4 MB
  float*          ws_phi   = (float*)(ws + (size_t)17 * (1 << 20));          // 8 MB
  float*          ws_psi   = (float*)(ws + (size_t)25 * (1 << 20));          // 8 MB
  float*          ws_alp   = (float*)(ws + (size_t)33 * (1 << 20));          // 8 MB
  float4*         ws_pkg   = (float4*)(ws + (size_t)41 * (1 << 20));         // 256 KB
  unsigned short* ws_wpk   = (unsigned short*)(ws + (size_t)41 * (1 << 20) + (1 << 18)); // 512 KB
  unsigned short* ws_y_h = ws_xin_h;   // xin only live until topgemm; stream-ordered reuse
  unsigned short* ws_y_l = ws_xin_l;

  prep_kernel<<<(BB * NN) / 256, 256, 0, stream>>>(input_p, ws_pkg);
  wprep_kernel<<<64, 256, 0, stream>>>(d2_W, g1_W, g2_W, top_W, phi_W, psi_W, alpha_W, down_W,
                                       ws_wpk);
  xpose_kernel<<<dim3(NN / 64, CC / 64, BB), 256, 0, stream>>>(input_x, ws_xin_h, ws_xin_l);
  knn_kernel<<<dim3(NN / 64, BB), 512, 0, stream>>>(ws_pkg, ws_idx);
  topgemm_kernel<<<dim3(NN / 32, BB), 256, 0, stream>>>(ws_xin_h, ws_xin_l, ws_wpk, top_b,
                                                        ws_x_h, ws_x_l);
  pqa_kernel<<<dim3(NN / 32, BB), 256, 0, stream>>>(ws_x_h, ws_x_l, ws_wpk,
                                                    phi_b, psi_b, alpha_b,
                                                    ws_phi, ws_psi, ws_alp);
  fused_kernel<<<dim3(NN / TNP, BB), 256, 0, stream>>>(input_p, ws_idx, ws_phi, ws_psi, ws_alp,
                                                       ws_wpk, d1_W, d1_b, d2_b, g1_b, g2_b,
                                                       ws_y_h, ws_y_l);
  down_kernel<<<dim3(NN / 64, BB), 256, 0, stream>>>(ws_y_h, ws_y_l, ws_wpk, down_b,
                                                     input_x, out);
}

// Round 6
// 391.641 us; speedup vs baseline: 2.9146x; 1.0070x over previous
//
#include <hip/hip_runtime.h>
#include <hip/hip_bf16.h>

#define BB 4
#define CC 128
#define NN 4096
#define KK 16
#define FLT_BIG 3.402823466e+38f

typedef __attribute__((ext_vector_type(8))) short short8v;
typedef __attribute__((ext_vector_type(4))) short short4v;
typedef __attribute__((ext_vector_type(4))) float f32x4;

__device__ __forceinline__ unsigned short f2b(float x) {   // RNE f32->bf16 (manual)
  union { float f; unsigned u; } v; v.f = x;
  unsigned r = v.u + 0x7fffu + ((v.u >> 16) & 1u);
  return (unsigned short)(r >> 16);
}
__device__ __forceinline__ float b2f(unsigned short h) {
  union { float f; unsigned u; } v; v.u = ((unsigned)h) << 16; return v.f;
}
// packed RNE pair: [15:0]=bf16(a), [31:16]=bf16(b)  (v_cvt_pk_bf16_f32)
__device__ __forceinline__ unsigned pkrn(float a, float b) {
  __hip_bfloat162 t = __float22bfloat162_rn(make_float2(a, b));
  union { __hip_bfloat162 h; unsigned u; } c; c.h = t; return c.u;
}
// split (a,b) into packed hi + packed lo bf16 pairs
__device__ __forceinline__ void split2(float a, float b, unsigned& h, unsigned& l) {
  h = pkrn(a, b);
  union { unsigned u; float f; } lo, hi2;
  lo.u = h << 16;
  hi2.u = h & 0xffff0000u;
  l = pkrn(a - lo.f, b - hi2.f);
}

// ---- shared distance: identical instruction sequence everywhere (bit-exact re-eval) ----
__device__ __forceinline__ float dist4(const float4 q, const float4 c) {
  float t = __fmaf_rn(q.x, c.x, __fmaf_rn(q.y, c.y, __fmul_rn(q.z, c.z)));
  return __fmaf_rn(-2.f, t, q.w + c.w);
}

// ================= setup: prep(pkg) + wprep(weight frags) + xpose(xin planes) =============
// grid 640: [0,64) prep, [64,128) wprep, [128,640) xpose
__global__ __launch_bounds__(256) void setup_kernel(
    const float* __restrict__ p, const float* __restrict__ x,
    const float* __restrict__ d2W, const float* __restrict__ g1W,
    const float* __restrict__ g2W, const float* __restrict__ topW,
    const float* __restrict__ phiW, const float* __restrict__ psiW,
    const float* __restrict__ alpW, const float* __restrict__ dnW,
    float4* __restrict__ pkg, unsigned short* __restrict__ wpk,
    unsigned short* __restrict__ xh, unsigned short* __restrict__ xl)
{
  __shared__ float t[64][65];
  const int bid = blockIdx.x, tid = threadIdx.x;
  if (bid < 64) {            // ---- prep ----
    int i = bid * 256 + tid;
    int b = i >> 12, m = i & (NN - 1);
    const float* pb = p + (size_t)b * 3 * NN;
    float xx = pb[m], yy = pb[NN + m], zz = pb[2 * NN + m];
    pkg[i] = make_float4(xx, yy, zz, __fmaf_rn(xx, xx, __fmaf_rn(yy, yy, __fmul_rn(zz, zz))));
  } else if (bid < 128) {    // ---- wprep: mats 0=d2 1=g1 2=g2 3=top 4=phi 5=psi 6=alpha 7=down
    int tt = (bid - 64) * 256 + tid;       // 0..16383
    int mat = tt >> 11, r = tt & 2047;
    int ct = r >> 8, ks = (r >> 6) & 3, lane = r & 63;
    const float* W;
    switch (mat) {
      case 0: W = d2W; break;  case 1: W = g1W; break;
      case 2: W = g2W; break;  case 3: W = topW; break;
      case 4: W = phiW; break; case 5: W = psiW; break;
      case 6: W = alpW; break; default: W = dnW; break;
    }
    int row = ct * 16 + (lane & 15);
    int k0 = ks * 32 + (lane >> 4) * 8;
    const float* src = &W[row * 128 + k0];
    unsigned short* dh = &wpk[((size_t)(((mat * 2 + 0) * 8 + ct) * 4 + ks) * 64 + lane) * 8];
    unsigned short* dl = &wpk[((size_t)(((mat * 2 + 1) * 8 + ct) * 4 + ks) * 64 + lane) * 8];
#pragma unroll
    for (int e = 0; e < 8; ++e) {
      float v = src[e];
      unsigned short h = f2b(v);
      dh[e] = h;
      dl[e] = f2b(v - b2f(h));
    }
  } else {                   // ---- xpose: input_x [B][C][N] -> hi/lo planes [B][N][C]
    int bid2 = bid - 128;
    int nb = bid2 & 63, cb = (bid2 >> 6) & 1, b = bid2 >> 7;
    const int c0 = cb * 64, n0 = nb * 64;
    const int tn = tid & 63, tq = tid >> 6;
    const float* xb = x + ((size_t)b * CC + c0) * NN + n0;
#pragma unroll
    for (int i = 0; i < 16; ++i) {
      int c = tq * 16 + i;
      t[c][tn] = xb[(size_t)c * NN + tn];
    }
    __syncthreads();
#pragma unroll
    for (int i = 0; i < 16; ++i) {
      int nl = tq * 16 + i;
      float v = t[tn][nl];
      unsigned short h = f2b(v);
      size_t o = ((size_t)b * NN + n0 + nl) * CC + c0 + tn;
      xh[o] = h;
      xl[o] = f2b(v - b2f(h));
    }
  }
}

// ================= KNN: exact 16-NN set (order-free; boundary ties -> lowest index) ======
__global__ __launch_bounds__(512, 2) void knn_kernel(const float4* __restrict__ pkg,
                                                     int* __restrict__ outidx)
{
  __shared__ float BD[8][64][17];
  __shared__ float TS[64];
  __shared__ int   CNT[64];
  __shared__ float COLd[64][20];
  __shared__ int   COLi[64][20];
  const int b = blockIdx.y;
  const int tid = threadIdx.x;
  const int lane = tid & 63;
  const int w = tid >> 6;
  const int n = blockIdx.x * 64 + lane;
  const float4* PB = pkg + (size_t)b * NN;
  const float4 qc = PB[n];
  if (tid < 64) CNT[tid] = 0;

  float bd[16];
#pragma unroll
  for (int t = 0; t < 16; ++t) bd[t] = FLT_BIG;
  const int m0 = w * 512;
#pragma unroll 4
  for (int m = m0; m < m0 + 512; ++m) {
    float4 c = PB[m];
    float d = dist4(qc, c);
#pragma unroll
    for (int t = 15; t >= 1; --t) bd[t] = __builtin_amdgcn_fmed3f(bd[t - 1], d, bd[t]);
    bd[0] = fminf(bd[0], d);
  }
#pragma unroll
  for (int t = 0; t < 16; ++t) BD[w][lane][t] = bd[t];
  __syncthreads();

  if (tid < 64) {
    const int q = tid;
    int h0 = 0, h1 = 0, h2 = 0, h3 = 0, h4 = 0, h5 = 0, h6 = 0, h7 = 0;
    float mv = FLT_BIG;
#pragma unroll 1
    for (int r = 0; r < 16; ++r) {
      float v0 = BD[0][q][h0], v1 = BD[1][q][h1], v2 = BD[2][q][h2], v3 = BD[3][q][h3];
      float v4 = BD[4][q][h4], v5 = BD[5][q][h5], v6 = BD[6][q][h6], v7 = BD[7][q][h7];
      mv = v0; int mw = 0;
      if (v1 < mv) { mv = v1; mw = 1; }
      if (v2 < mv) { mv = v2; mw = 2; }
      if (v3 < mv) { mv = v3; mw = 3; }
      if (v4 < mv) { mv = v4; mw = 4; }
      if (v5 < mv) { mv = v5; mw = 5; }
      if (v6 < mv) { mv = v6; mw = 6; }
      if (v7 < mv) { mv = v7; mw = 7; }
      h0 += (mw == 0); h1 += (mw == 1); h2 += (mw == 2); h3 += (mw == 3);
      h4 += (mw == 4); h5 += (mw == 5); h6 += (mw == 6); h7 += (mw == 7);
    }
    TS[q] = mv;
  }
  __syncthreads();

  {
    const float thr = TS[lane];
#pragma unroll 4
    for (int m = m0; m < m0 + 512; ++m) {
      float4 c = PB[m];
      float d = dist4(qc, c);
      if (d <= thr) {
        int pos = atomicAdd(&CNT[lane], 1);
        if (pos < 20) { COLd[lane][pos] = d; COLi[lane][pos] = m; }
      }
    }
  }
  __syncthreads();

  if (tid < 64) {
    const int q = tid;
    int c = CNT[q]; if (c > 20) c = 20;
    int* op = outidx + ((size_t)b * NN + blockIdx.x * 64 + q) * KK;
    if (c == KK) {
#pragma unroll
      for (int o = 0; o < KK; ++o) op[o] = COLi[q][o];
    } else {
      const float T = TS[q];
      int less = 0;
      for (int s = 0; s < c; ++s) less += (COLd[q][s] < T);
      int need = KK - less;
      int o = 0;
      for (int s = 0; s < c; ++s)
        if (COLd[q][s] < T) op[o++] = COLi[q][s];
      for (int s = 0; s < c; ++s) {
        if (COLd[q][s] == T) {
          int idx = COLi[q][s];
          int rank = 0;
          for (int s2 = 0; s2 < c; ++s2)
            rank += (COLd[q][s2] == T && COLi[q][s2] < idx);
          if (rank < need) op[o++] = idx;
        }
      }
    }
  }
}

// ================= feat: x = top(xin) in LDS; then phi/psi (f32) + alpha (bf16) ==========
// grid (NN/32, BB); block 256 = 4 waves; wave: nt=w&1 (16 n-rows), cq=w>>1 (col half)
__global__ __launch_bounds__(256) void feat_kernel(
    const unsigned short* __restrict__ xh, const unsigned short* __restrict__ xl,
    const unsigned short* __restrict__ wpk,
    const float* __restrict__ topb, const float* __restrict__ phib,
    const float* __restrict__ psib, const float* __restrict__ alpb,
    float* __restrict__ phit, float* __restrict__ psit,
    unsigned short* __restrict__ alpt)
{
  __shared__ float xtile[32][129];
  const int b = blockIdx.y, n0 = blockIdx.x * 32;
  const int tid = threadIdx.x, l = tid & 63, w = tid >> 6;
  const int lr = l & 15, lh = l >> 4;
  const int nt = w & 1, cq = w >> 1;
  // ---- phase 1: x rows (nt half) into LDS ----
  {
    const int nrow = n0 + nt * 16 + lr;
    const unsigned short* xhp = xh + ((size_t)b * NN + nrow) * CC;
    const unsigned short* xlp = xl + ((size_t)b * NN + nrow) * CC;
    short8v Ah[4], Al[4];
#pragma unroll
    for (int ks = 0; ks < 4; ++ks) {
      Ah[ks] = *(const short8v*)&xhp[ks * 32 + lh * 8];
      Al[ks] = *(const short8v*)&xlp[ks * 32 + lh * 8];
    }
    const int nDl = nt * 16 + lh * 4;
#pragma unroll
    for (int cc = 0; cc < 4; ++cc) {
      const int colt = cq * 4 + cc;
      f32x4 acc = (f32x4){0.f, 0.f, 0.f, 0.f};
#pragma unroll
      for (int ks = 0; ks < 4; ++ks) {
        short8v Wh = *(const short8v*)&wpk[((size_t)(((3 * 2 + 0) * 8 + colt) * 4 + ks) * 64 + l) * 8];
        short8v Wl = *(const short8v*)&wpk[((size_t)(((3 * 2 + 1) * 8 + colt) * 4 + ks) * 64 + l) * 8];
        acc = __builtin_amdgcn_mfma_f32_16x16x32_bf16(Ah[ks], Wh, acc, 0, 0, 0);
        acc = __builtin_amdgcn_mfma_f32_16x16x32_bf16(Al[ks], Wh, acc, 0, 0, 0);
        acc = __builtin_amdgcn_mfma_f32_16x16x32_bf16(Ah[ks], Wl, acc, 0, 0, 0);
      }
      float bv = topb[colt * 16 + lr];
#pragma unroll
      for (int r = 0; r < 4; ++r) xtile[nDl + r][colt * 16 + lr] = acc[r] + bv;
    }
  }
  __syncthreads();
  // ---- phase 2: rebuild pair A-frags from LDS, run phi/psi/alpha ----
  short8v Ah[4], Al[4];
  {
    const int rl = nt * 16 + lr;
#pragma unroll
    for (int ks = 0; ks < 4; ++ks) {
      union { short8v s; unsigned u[4]; } H, L;
#pragma unroll
      for (int i = 0; i < 4; ++i) {
        float a = xtile[rl][ks * 32 + lh * 8 + 2 * i];
        float bb = xtile[rl][ks * 32 + lh * 8 + 2 * i + 1];
        split2(a, bb, H.u[i], L.u[i]);
      }
      Ah[ks] = H.s; Al[ks] = L.s;
    }
  }
  const int nD = n0 + nt * 16 + lh * 4;
#pragma unroll
  for (int m = 0; m < 3; ++m) {
    const int mat = 4 + m;
    const float* bias = (m == 0) ? phib : (m == 1) ? psib : alpb;
#pragma unroll
    for (int cc = 0; cc < 4; ++cc) {
      const int colt = cq * 4 + cc;
      f32x4 acc = (f32x4){0.f, 0.f, 0.f, 0.f};
#pragma unroll
      for (int ks = 0; ks < 4; ++ks) {
        short8v Wh = *(const short8v*)&wpk[((size_t)(((mat * 2 + 0) * 8 + colt) * 4 + ks) * 64 + l) * 8];
        short8v Wl = *(const short8v*)&wpk[((size_t)(((mat * 2 + 1) * 8 + colt) * 4 + ks) * 64 + l) * 8];
        acc = __builtin_amdgcn_mfma_f32_16x16x32_bf16(Ah[ks], Wh, acc, 0, 0, 0);
        acc = __builtin_amdgcn_mfma_f32_16x16x32_bf16(Al[ks], Wh, acc, 0, 0, 0);
        acc = __builtin_amdgcn_mfma_f32_16x16x32_bf16(Ah[ks], Wl, acc, 0, 0, 0);
      }
      float bv = bias[colt * 16 + lr];
      if (m == 2) {
#pragma unroll
        for (int r = 0; r < 4; ++r)
          alpt[((size_t)b * NN + nD + r) * CC + colt * 16 + lr] = f2b(acc[r] + bv);
      } else {
        float* outp = (m == 0) ? phit : psit;
#pragma unroll
        for (int r = 0; r < 4; ++r)
          outp[((size_t)b * NN + nD + r) * CC + colt * 16 + lr] = acc[r] + bv;
      }
    }
  }
}

// ================= down: out = dnW @ y + b + res  (y from pair planes) ==================
__global__ __launch_bounds__(256) void down_kernel(
    const unsigned short* __restrict__ yh, const unsigned short* __restrict__ yl,
    const unsigned short* __restrict__ wpk,
    const float* __restrict__ bias, const float* __restrict__ res,
    float* __restrict__ out)
{
  const int b = blockIdx.y, n0 = blockIdx.x * 64;
  const int tid = threadIdx.x, l = tid & 63, w = tid >> 6;
  const int lr = l & 15, lh = l >> 4;
  short8v Ah[2][4], Al[2][4];
#pragma unroll
  for (int ct = 0; ct < 2; ++ct)
#pragma unroll
    for (int ks = 0; ks < 4; ++ks) {
      Ah[ct][ks] = *(const short8v*)&wpk[((size_t)(((7 * 2 + 0) * 8 + (2 * w + ct)) * 4 + ks) * 64 + l) * 8];
      Al[ct][ks] = *(const short8v*)&wpk[((size_t)(((7 * 2 + 1) * 8 + (2 * w + ct)) * 4 + ks) * 64 + l) * 8];
    }
  f32x4 acc[2][4];
#pragma unroll
  for (int colt = 0; colt < 4; ++colt) {
    const int n = n0 + colt * 16 + lr;
    const unsigned short* yhp = yh + ((size_t)b * NN + n) * CC;
    const unsigned short* ylp = yl + ((size_t)b * NN + n) * CC;
#pragma unroll
    for (int ct = 0; ct < 2; ++ct) acc[ct][colt] = (f32x4){0.f, 0.f, 0.f, 0.f};
#pragma unroll
    for (int ks = 0; ks < 4; ++ks) {
      short8v Bh = *(const short8v*)&yhp[ks * 32 + lh * 8];
      short8v Bl = *(const short8v*)&ylp[ks * 32 + lh * 8];
#pragma unroll
      for (int ct = 0; ct < 2; ++ct) {
        acc[ct][colt] = __builtin_amdgcn_mfma_f32_16x16x32_bf16(Ah[ct][ks], Bh, acc[ct][colt], 0, 0, 0);
        acc[ct][colt] = __builtin_amdgcn_mfma_f32_16x16x32_bf16(Ah[ct][ks], Bl, acc[ct][colt], 0, 0, 0);
        acc[ct][colt] = __builtin_amdgcn_mfma_f32_16x16x32_bf16(Al[ct][ks], Bh, acc[ct][colt], 0, 0, 0);
      }
    }
  }
#pragma unroll
  for (int ct = 0; ct < 2; ++ct) {
    const int c0 = 32 * w + ct * 16 + lh * 4;
#pragma unroll
    for (int r = 0; r < 4; ++r) {
      float bv = bias[c0 + r];
#pragma unroll
      for (int colt = 0; colt < 4; ++colt) {
        size_t o = ((size_t)b * CC + c0 + r) * NN + n0 + colt * 16 + lr;
        out[o] = acc[ct][colt][r] + bv + res[o];
      }
    }
  }
}

// ================= Fused core: cvt_pk split, psi/alp prefetch, LDS-staged y write =========
#define TNP 4
__global__ __launch_bounds__(256, 4) void fused_kernel(
    const float* __restrict__ p, const int* __restrict__ idxg,
    const float* __restrict__ phi_t, const float* __restrict__ psi_t,
    const unsigned short* __restrict__ alp_b, const unsigned short* __restrict__ wpk,
    const float* __restrict__ d1W, const float* __restrict__ d1b,
    const float* __restrict__ d2b, const float* __restrict__ g1b,
    const float* __restrict__ g2b,
    unsigned short* __restrict__ yh, unsigned short* __restrict__ yl)
{
  __shared__ __align__(16) unsigned short act[2][64][136];  // [hi/lo][col][c]
  __shared__ int idxs[64];
  const int b = blockIdx.y;
  const int n0 = blockIdx.x * TNP;
  const int tid = threadIdx.x;
  const int l = tid & 63, w = tid >> 6;
  const int lr = l & 15, lh = l >> 4;

  if (tid < 64) idxs[tid] = idxg[((size_t)b * NN + n0 + (tid >> 4)) * KK + (tid & 15)];
  __syncthreads();

  // ---------- stage 0: rel -> pos1 = relu(d1W rel + d1b), hi/lo into act ----------
  {
    const int col = tid & 63, q = tid >> 6;
    const int pt = col >> 4;
    const int j = idxs[col];
    const float* pb = p + (size_t)b * 3 * NN;
    float r0 = pb[n0 + pt] - pb[j];
    float r1 = pb[NN + n0 + pt] - pb[NN + j];
    float r2 = pb[2 * NN + n0 + pt] - pb[2 * NN + j];
#pragma unroll
    for (int ch = 0; ch < 4; ++ch) {
      int c0 = q * 32 + ch * 8;
      float v[8];
#pragma unroll
      for (int e = 0; e < 8; ++e) {
        int c = c0 + e;
        v[e] = fmaxf(d1W[c * 3 + 0] * r0 + d1W[c * 3 + 1] * r1 + d1W[c * 3 + 2] * r2 + d1b[c], 0.f);
      }
      uint4 H, L;
      split2(v[0], v[1], H.x, L.x); split2(v[2], v[3], H.y, L.y);
      split2(v[4], v[5], H.z, L.z); split2(v[6], v[7], H.w, L.w);
      *(uint4*)&act[0][col][c0] = H;
      *(uint4*)&act[1][col][c0] = L;
    }
  }
  __syncthreads();

  int idxv[TNP];
#pragma unroll
  for (int colt = 0; colt < TNP; ++colt) idxv[colt] = idxs[colt * 16 + lr];

  f32x4 acc[2][TNP];
  short8v Af[2][4];

#define LOADA(MAT) do {                                                                 \
  _Pragma("unroll") for (int ct = 0; ct < 2; ++ct)                                      \
    _Pragma("unroll") for (int ks = 0; ks < 4; ++ks)                                    \
      Af[ct][ks] = *(const short8v*)&wpk[((size_t)((((MAT) * 2 + 0) * 8 + (2 * w + ct)) * 4 + ks) * 64 + l) * 8]; \
  } while (0)

#define MMUL() do {                                                                     \
  _Pragma("unroll") for (int ct = 0; ct < 2; ++ct)                                      \
    _Pragma("unroll") for (int colt = 0; colt < TNP; ++colt)                            \
      acc[ct][colt] = (f32x4){0.f, 0.f, 0.f, 0.f};                                      \
  _Pragma("unroll") for (int colt = 0; colt < TNP; ++colt) {                            \
    short8v Bh[4], Bl[4];                                                               \
    _Pragma("unroll") for (int ks = 0; ks < 4; ++ks) {                                  \
      Bh[ks] = *(const short8v*)&act[0][colt * 16 + lr][ks * 32 + lh * 8];              \
      Bl[ks] = *(const short8v*)&act[1][colt * 16 + lr][ks * 32 + lh * 8];              \
    }                                                                                   \
    _Pragma("unroll") for (int ct = 0; ct < 2; ++ct)                                    \
      _Pragma("unroll") for (int ks = 0; ks < 4; ++ks) {                                \
        acc[ct][colt] = __builtin_amdgcn_mfma_f32_16x16x32_bf16(Af[ct][ks], Bh[ks],     \
                                                                acc[ct][colt], 0, 0, 0); \
        acc[ct][colt] = __builtin_amdgcn_mfma_f32_16x16x32_bf16(Af[ct][ks], Bl[ks],     \
                                                                acc[ct][colt], 0, 0, 0); \
      }                                                                                 \
  } } while (0)

  // ---------- prefetch psi gathers (hidden under d2 MMUL) ----------
  f32x4 psiv[2][TNP];
#pragma unroll
  for (int colt = 0; colt < TNP; ++colt) {
    size_t srow = ((size_t)b * NN + idxv[colt]) * CC;
#pragma unroll
    for (int ct = 0; ct < 2; ++ct)
      psiv[ct][colt] = *(const f32x4*)&psi_t[srow + 32 * w + ct * 16 + lh * 4];
  }

  // ---------- d2: pos = d2W @ pos1 + d2b (kept in registers) ----------
  LOADA(0); MMUL();
  float pos[2][TNP][4];
#pragma unroll
  for (int ct = 0; ct < 2; ++ct) {
    f32x4 bv = *(const f32x4*)&d2b[32 * w + ct * 16 + lh * 4];
#pragma unroll
    for (int colt = 0; colt < TNP; ++colt)
#pragma unroll
      for (int r = 0; r < 4; ++r) pos[ct][colt][r] = acc[ct][colt][r] + bv[r];
  }
  __syncthreads();   // all waves done reading pos1

  // ---------- ain = pos + phi[n] - psi[idx] -> act ----------
#pragma unroll
  for (int colt = 0; colt < TNP; ++colt) {
    size_t prow = ((size_t)b * NN + n0 + colt) * CC;
#pragma unroll
    for (int ct = 0; ct < 2; ++ct) {
      int c0 = 32 * w + ct * 16 + lh * 4;
      f32x4 ph = *(const f32x4*)&phi_t[prow + c0];
      float v[4];
#pragma unroll
      for (int r = 0; r < 4; ++r) v[r] = pos[ct][colt][r] + ph[r] - psiv[ct][colt][r];
      uint2 H, L;
      split2(v[0], v[1], H.x, L.x); split2(v[2], v[3], H.y, L.y);
      *(uint2*)&act[0][colt * 16 + lr][c0] = H;
      *(uint2*)&act[1][colt * 16 + lr][c0] = L;
    }
  }
  __syncthreads();

  // ---------- prefetch alpha (bf16) gathers (hidden under g1/g2 MMULs) ----------
  uint2 ualp[2][TNP];
#pragma unroll
  for (int colt = 0; colt < TNP; ++colt) {
    size_t arow = ((size_t)b * NN + idxv[colt]) * CC;
#pragma unroll
    for (int ct = 0; ct < 2; ++ct)
      ualp[ct][colt] = *(const uint2*)&alp_b[arow + 32 * w + ct * 16 + lh * 4];
  }

  // ---------- g1: h = relu(g1W @ ain + g1b) -> act ----------
  LOADA(1); MMUL();
  __syncthreads();   // all waves done reading ain
#pragma unroll
  for (int ct = 0; ct < 2; ++ct) {
    f32x4 bv = *(const f32x4*)&g1b[32 * w + ct * 16 + lh * 4];
    int c0 = 32 * w + ct * 16 + lh * 4;
#pragma unroll
    for (int colt = 0; colt < TNP; ++colt) {
      float v[4];
#pragma unroll
      for (int r = 0; r < 4; ++r) v[r] = fmaxf(acc[ct][colt][r] + bv[r], 0.f);
      uint2 H, L;
      split2(v[0], v[1], H.x, L.x); split2(v[2], v[3], H.y, L.y);
      *(uint2*)&act[0][colt * 16 + lr][c0] = H;
      *(uint2*)&act[1][colt * 16 + lr][c0] = L;
    }
  }
  __syncthreads();

  // ---------- g2: attn = g2W @ h + g2b ----------
  LOADA(2); MMUL();
#pragma unroll
  for (int ct = 0; ct < 2; ++ct) {
    f32x4 bv = *(const f32x4*)&g2b[32 * w + ct * 16 + lh * 4];
#pragma unroll
    for (int colt = 0; colt < TNP; ++colt)
#pragma unroll
      for (int r = 0; r < 4; ++r) acc[ct][colt][r] += bv[r];
  }

  // ---------- softmax over k (= lr lanes within each colt) ----------
#pragma unroll
  for (int ct = 0; ct < 2; ++ct)
#pragma unroll
    for (int colt = 0; colt < TNP; ++colt)
#pragma unroll
      for (int r = 0; r < 4; ++r) {
        float a = acc[ct][colt][r];
        float m = a;
        m = fmaxf(m, __shfl_xor(m, 1));
        m = fmaxf(m, __shfl_xor(m, 2));
        m = fmaxf(m, __shfl_xor(m, 4));
        m = fmaxf(m, __shfl_xor(m, 8));
        float e = __expf(a - m);
        float s = e;
        s += __shfl_xor(s, 1);
        s += __shfl_xor(s, 2);
        s += __shfl_xor(s, 4);
        s += __shfl_xor(s, 8);
        acc[ct][colt][r] = e / s;
      }

  __syncthreads();   // all waves past their last act read (g2 MMUL) -> safe to reuse act
  unsigned short* yst = &act[0][0][0];   // staging: rows 0..3 = yh[colt], rows 4..7 = yl

  // ---------- combine: y_t[n][c] = sum_k wgt * (alpha[idx] + pos) ----------
#pragma unroll
  for (int colt = 0; colt < TNP; ++colt) {
#pragma unroll
    for (int ct = 0; ct < 2; ++ct) {
      int c0 = 32 * w + ct * 16 + lh * 4;
      uint2 ua = ualp[ct][colt];
      union { unsigned u; float f; } a0, a1, a2, a3;
      a0.u = ua.x << 16; a1.u = ua.x & 0xffff0000u;
      a2.u = ua.y << 16; a3.u = ua.y & 0xffff0000u;
      float av[4] = {a0.f, a1.f, a2.f, a3.f};
      float yv[4];
#pragma unroll
      for (int r = 0; r < 4; ++r) {
        float part = acc[ct][colt][r] * (av[r] + pos[ct][colt][r]);
        part += __shfl_xor(part, 1);
        part += __shfl_xor(part, 2);
        part += __shfl_xor(part, 4);
        part += __shfl_xor(part, 8);
        yv[r] = part;
      }
      if (lr == 0) {
        uint2 H, L;
        split2(yv[0], yv[1], H.x, L.x); split2(yv[2], yv[3], H.y, L.y);
        *(uint2*)&yst[(size_t)colt * 128 + c0] = H;
        *(uint2*)&yst[(size_t)(4 + colt) * 128 + c0] = L;
      }
    }
  }
  __syncthreads();
  // ---------- coalesced y writeout: 2 KB, 16B per thread ----------
  if (tid < 128) {
    int plane = tid >> 6, row = (tid >> 4) & 3, chunk = tid & 15;
    uint4 v4 = *(const uint4*)&yst[(size_t)(plane * 4 + row) * 128 + chunk * 8];
    unsigned short* dst = (plane ? yl : yh) + ((size_t)b * NN + n0 + row) * CC + chunk * 8;
    *(uint4*)dst = v4;
  }
#undef LOADA
#undef MMUL
}

// =============================================================================================
extern "C" void kernel_launch(void* const* d_in, const int* in_sizes, int n_in,
                              void* d_out, int out_size, void* d_ws, size_t ws_size,
                              hipStream_t stream) {
  const float* input_p = (const float*)d_in[0];
  const float* input_x = (const float*)d_in[1];
  const float* top_W   = (const float*)d_in[2];  const float* top_b   = (const float*)d_in[3];
  const float* down_W  = (const float*)d_in[4];  const float* down_b  = (const float*)d_in[5];
  const float* phi_W   = (const float*)d_in[6];  const float* phi_b   = (const float*)d_in[7];
  const float* psi_W   = (const float*)d_in[8];  const float* psi_b   = (const float*)d_in[9];
  const float* alpha_W = (const float*)d_in[10]; const float* alpha_b = (const float*)d_in[11];
  const float* g1_W    = (const float*)d_in[12]; const float* g1_b    = (const float*)d_in[13];
  const float* g2_W    = (const float*)d_in[14]; const float* g2_b    = (const float*)d_in[15];
  const float* d1_W    = (const float*)d_in[16]; const float* d1_b    = (const float*)d_in[17];
  const float* d2_W    = (const float*)d_in[18]; const float* d2_b    = (const float*)d_in[19];
  float* out = (float*)d_out;

  char* ws = (char*)d_ws;
  int*            ws_idx   = (int*)ws;                                         // 1 MB
  unsigned short* ws_xin_h = (unsigned short*)(ws + (size_t)1  * (1 << 20));   // 4 MB (reused as y_h)
  unsigned short* ws_xin_l = (unsigned short*)(ws + (size_t)5  * (1 << 20));   // 4 MB (reused as y_l)
  float*          ws_phi   = (float*)(ws + (size_t)9  * (1 << 20));            // 8 MB
  float*          ws_psi   = (float*)(ws + (size_t)17 * (1 << 20));            // 8 MB
  unsigned short* ws_alp   = (unsigned short*)(ws + (size_t)25 * (1 << 20));   // 4 MB (bf16)
  float4*         ws_pkg   = (float4*)(ws + (size_t)29 * (1 << 20));           // 256 KB
  unsigned short* ws_wpk   = (unsigned short*)(ws + (size_t)29 * (1 << 20) + (1 << 18)); // 512 KB
  unsigned short* ws_y_h = ws_xin_h;   // xin consumed by feat; stream-ordered reuse
  unsigned short* ws_y_l = ws_xin_l;

  setup_kernel<<<640, 256, 0, stream>>>(input_p, input_x, d2_W, g1_W, g2_W, top_W,
                                        phi_W, psi_W, alpha_W, down_W,
                                        ws_pkg, ws_wpk, ws_xin_h, ws_xin_l);
  knn_kernel<<<dim3(NN / 64, BB), 512, 0, stream>>>(ws_pkg, ws_idx);
  feat_kernel<<<dim3(NN / 32, BB), 256, 0, stream>>>(ws_xin_h, ws_xin_l, ws_wpk,
                                                     top_b, phi_b, psi_b, alpha_b,
                                                     ws_phi, ws_psi, ws_alp);
  fused_kernel<<<dim3(NN / TNP, BB), 256, 0, stream>>>(input_p, ws_idx, ws_phi, ws_psi, ws_alp,
                                                       ws_wpk, d1_W, d1_b, d2_b, g1_b, g2_b,
                                                       ws_y_h, ws_y_l);
  down_kernel<<<dim3(NN / 64, BB), 256, 0, stream>>>(ws_y_h, ws_y_l, ws_wpk, down_b,
                                                     input_x, out);
}